// Round 4
// baseline (635.314 us; speedup 1.0000x reference)
//
#include <hip/hip_runtime.h>
#include <hip/hip_bf16.h>

// Problem constants
static constexpr int B_   = 8;
static constexpr int C_   = 256;
static constexpr int N_   = 8192;
static constexpr int G_   = 4;
static constexpr int GS_  = 64;   // group size (= H)
static constexpr int TH_  = 192;  // 3*H
static constexpr int NT1  = 16;   // n-tile for k_pre
static constexpr int NT3  = 32;   // n-tile for k_out

// Chunked-warm-up scan parallelization:
static constexpr int CHUNK = 256;        // steps written per workgroup
static constexpr int WARM  = 128;        // warm-up steps (worst-case contraction ~0.91/step)
static constexpr int NCHUNKS = N_ / CHUNK;  // 32

typedef float v2f __attribute__((ext_vector_type(2)));
__device__ __forceinline__ v2f mkv2(float a, float b) { v2f r; r.x = a; r.y = b; return r; }

__device__ __forceinline__ float fsigmoid(float x) {
  return __builtin_amdgcn_rcpf(1.0f + __expf(-x));
}
__device__ __forceinline__ float ftanh(float x) {
  float e = __expf(2.0f * x);                       // inf-safe: rcp(inf)=0
  return 1.0f - 2.0f * __builtin_amdgcn_rcpf(e + 1.0f);
}
__device__ __forceinline__ unsigned short bf16bits(float v) {
  __hip_bfloat16 h = __float2bfloat16(v);
  return __builtin_bit_cast(unsigned short, h);
}
__device__ __forceinline__ float bf16tof(unsigned short u) {
  return __uint_as_float(((unsigned int)u) << 16);
}

// ---------------- Kernel 1: input-gate precompute --------------------------
// pre[b][g][n][k] = sum_i x[b, g*64+i, n] * W_ih[g][k][i] + b_ih[g][k]  (bf16)
// Thread owns 2 adjacent rows x 8 n  -> halves LDS broadcast reads per FMA.
__global__ __launch_bounds__(192) void k_pre(const float* __restrict__ x,
                                             const float* __restrict__ W_ih,
                                             const float* __restrict__ b_ih,
                                             __hip_bfloat16* __restrict__ pre) {
  __shared__ __align__(16) float xt[GS_][NT1];
  const int bid = blockIdx.x;
  const int nb  = bid & 511;            // N/NT1 = 512
  const int bg  = bid >> 9;             // 0..31
  const int g   = bg & 3, b = bg >> 2;
  const int t   = threadIdx.x;          // 0..191
  const int np  = (t >= 96) ? 1 : 0;    // n-slice (8 n each)
  const int rp  = t - np * 96;          // 0..95 row-pair id
  const int r0  = 2 * rp;
  const int n0  = nb * NT1;

  // stage x tile [64 i][16 n]
  for (int idx = t; idx < GS_ * NT1; idx += 192) {
    int i = idx >> 4, j = idx & 15;
    xt[i][j] = x[((size_t)(b * C_ + g * GS_ + i)) * N_ + n0 + j];
  }
  // two W_ih rows -> 128 regs
  float w0[GS_], w1[GS_];
  const float4* wp0 = (const float4*)(W_ih + ((size_t)g * TH_ + r0) * GS_);
  const float4* wp1 = (const float4*)(W_ih + ((size_t)g * TH_ + r0 + 1) * GS_);
#pragma unroll
  for (int i4 = 0; i4 < 16; ++i4) {
    float4 a = wp0[i4];
    w0[4*i4+0]=a.x; w0[4*i4+1]=a.y; w0[4*i4+2]=a.z; w0[4*i4+3]=a.w;
    float4 c = wp1[i4];
    w1[4*i4+0]=c.x; w1[4*i4+1]=c.y; w1[4*i4+2]=c.z; w1[4*i4+3]=c.w;
  }
  v2f acc0[4], acc1[4];
  const float bi0 = b_ih[g * TH_ + r0];
  const float bi1 = b_ih[g * TH_ + r0 + 1];
#pragma unroll
  for (int j = 0; j < 4; ++j) { acc0[j] = mkv2(bi0, bi0); acc1[j] = mkv2(bi1, bi1); }
  __syncthreads();

#pragma unroll
  for (int i = 0; i < GS_; ++i) {
    const float4* xr = (const float4*)&xt[i][np * 8];
    float4 xa = xr[0], xb = xr[1];
    v2f x0 = mkv2(xa.x, xa.y), x1 = mkv2(xa.z, xa.w);
    v2f x2 = mkv2(xb.x, xb.y), x3 = mkv2(xb.z, xb.w);
    v2f w0v = mkv2(w0[i], w0[i]), w1v = mkv2(w1[i], w1[i]);
    acc0[0] = __builtin_elementwise_fma(w0v, x0, acc0[0]);
    acc0[1] = __builtin_elementwise_fma(w0v, x1, acc0[1]);
    acc0[2] = __builtin_elementwise_fma(w0v, x2, acc0[2]);
    acc0[3] = __builtin_elementwise_fma(w0v, x3, acc0[3]);
    acc1[0] = __builtin_elementwise_fma(w1v, x0, acc1[0]);
    acc1[1] = __builtin_elementwise_fma(w1v, x1, acc1[1]);
    acc1[2] = __builtin_elementwise_fma(w1v, x2, acc1[2]);
    acc1[3] = __builtin_elementwise_fma(w1v, x3, acc1[3]);
  }
  // pack two adjacent rows into one dword store
  unsigned* po = (unsigned*)((unsigned short*)pre +
                             ((size_t)bg * N_ + n0 + np * 8) * TH_ + r0);
#pragma unroll
  for (int j = 0; j < 8; ++j) {
    unsigned pk = ((unsigned)bf16bits(acc1[j >> 1][j & 1]) << 16) |
                  (unsigned)bf16bits(acc0[j >> 1][j & 1]);
    po[(size_t)j * (TH_ / 2)] = pk;
  }
}

// ---------------- Kernel 2: sequential GRU scan (chunked warm-up) ----------
// ONE 64-lane wave per (bg, chunk): lane u owns unit u and all 3 gate rows
// (u, 64+u, 128+u) -> gates in registers, no barriers. Only h round-trips
// through LDS (1 ds_write + 16 uniform b128 reads per step).
__global__ __launch_bounds__(64, 1) void k_scan(const __hip_bfloat16* __restrict__ pre,
                                                const float* __restrict__ W_hh,
                                                const float* __restrict__ b_hh,
                                                __hip_bfloat16* __restrict__ hcat) {
  __shared__ __align__(16) float hbuf[GS_];
  const int bid = blockIdx.x;
  const int p   = bid & (NCHUNKS - 1);
  const int bg  = bid >> 5;
  const int g   = bg & 3, b = bg >> 2;
  const int u   = threadIdx.x;          // 0..63 = hidden unit

  const int n_lo    = p * CHUNK;
  const int n_end   = n_lo + CHUNK;
  const int n_start = (n_lo >= WARM) ? (n_lo - WARM) : 0;

  // 3 W_hh rows -> 96 v2f (192 VGPRs); launch_bounds(64,1) gives headroom
  v2f wR[32], wZ[32], wN[32];
  const float4* wpR = (const float4*)(W_hh + ((size_t)g * TH_ + u) * GS_);
  const float4* wpZ = (const float4*)(W_hh + ((size_t)g * TH_ + 64 + u) * GS_);
  const float4* wpN = (const float4*)(W_hh + ((size_t)g * TH_ + 128 + u) * GS_);
#pragma unroll
  for (int i4 = 0; i4 < 16; ++i4) {
    float4 v = wpR[i4]; wR[2*i4] = mkv2(v.x, v.y); wR[2*i4+1] = mkv2(v.z, v.w);
    float4 y = wpZ[i4]; wZ[2*i4] = mkv2(y.x, y.y); wZ[2*i4+1] = mkv2(y.z, y.w);
    float4 q = wpN[i4]; wN[2*i4] = mkv2(q.x, q.y); wN[2*i4+1] = mkv2(q.z, q.w);
  }
  const float bR = b_hh[g * TH_ + u];
  const float bZ = b_hh[g * TH_ + 64 + u];
  const float bN = b_hh[g * TH_ + 128 + u];

  const unsigned short* pb = (const unsigned short*)(pre + (size_t)bg * N_ * TH_);
  __hip_bfloat16* ho = hcat + (size_t)b * N_ * C_ + g * GS_ + u;

  float hcur = 0.0f;
  hbuf[u] = 0.0f;

  // 4-step prefetch blocks, explicit A/B buffers (static indexing only)
  const int c0 = n_start >> 2, c1 = n_end >> 2;
  unsigned short fRA[4], fZA[4], fNA[4], fRB[4], fZB[4], fNB[4];
#pragma unroll
  for (int k = 0; k < 4; ++k) {
    size_t o = (size_t)(c0 * 4 + k) * TH_;
    fRA[k] = pb[o + u]; fZA[k] = pb[o + 64 + u]; fNA[k] = pb[o + 128 + u];
  }

  for (int nc = c0; nc < c1; ++nc) {
    if (nc + 1 < c1) {
#pragma unroll
      for (int k = 0; k < 4; ++k) {
        size_t o = (size_t)((nc + 1) * 4 + k) * TH_;
        fRB[k] = pb[o + u]; fZB[k] = pb[o + 64 + u]; fNB[k] = pb[o + 128 + u];
      }
    }
#pragma unroll
    for (int k = 0; k < 4; ++k) {
      const int n = nc * 4 + k;
      float pR = bf16tof(fRA[k]);
      float pZ = bf16tof(fZA[k]);
      float pN = bf16tof(fNA[k]);
      // 3 dots over h (broadcast from LDS), 6 independent packed chains
      v2f aR0 = mkv2(0.f, 0.f), aR1 = aR0, aZ0 = aR0, aZ1 = aR0, aN0 = aR0, aN1 = aR0;
#pragma unroll
      for (int i8 = 0; i8 < 8; ++i8) {
        float4 hA = *(const float4*)&hbuf[i8 * 8 + 0];
        float4 hB = *(const float4*)&hbuf[i8 * 8 + 4];
        v2f h0 = mkv2(hA.x, hA.y), h1 = mkv2(hA.z, hA.w);
        v2f h2 = mkv2(hB.x, hB.y), h3 = mkv2(hB.z, hB.w);
        aR0 = __builtin_elementwise_fma(wR[4*i8+0], h0, aR0);
        aR1 = __builtin_elementwise_fma(wR[4*i8+1], h1, aR1);
        aR0 = __builtin_elementwise_fma(wR[4*i8+2], h2, aR0);
        aR1 = __builtin_elementwise_fma(wR[4*i8+3], h3, aR1);
        aZ0 = __builtin_elementwise_fma(wZ[4*i8+0], h0, aZ0);
        aZ1 = __builtin_elementwise_fma(wZ[4*i8+1], h1, aZ1);
        aZ0 = __builtin_elementwise_fma(wZ[4*i8+2], h2, aZ0);
        aZ1 = __builtin_elementwise_fma(wZ[4*i8+3], h3, aZ1);
        aN0 = __builtin_elementwise_fma(wN[4*i8+0], h0, aN0);
        aN1 = __builtin_elementwise_fma(wN[4*i8+1], h1, aN1);
        aN0 = __builtin_elementwise_fma(wN[4*i8+2], h2, aN0);
        aN1 = __builtin_elementwise_fma(wN[4*i8+3], h3, aN1);
      }
      v2f sR = aR0 + aR1, sZ = aZ0 + aZ1, sN = aN0 + aN1;
      float r  = fsigmoid(sR.x + sR.y + bR + pR);
      float z  = fsigmoid(sZ.x + sZ.y + bZ + pZ);
      float gN = sN.x + sN.y + bN;
      float nn = ftanh(fmaf(r, gN, pN));
      float hnew = fmaf(z, hcur - nn, nn);  // (1-z)*n + z*h
      hcur = hnew;
      hbuf[u] = hnew;                       // visible to next step (same wave, in-order DS)
      if (n >= n_lo) ho[(size_t)n * C_] = __float2bfloat16(hnew);
    }
#pragma unroll
    for (int k = 0; k < 4; ++k) { fRA[k] = fRB[k]; fZA[k] = fZB[k]; fNA[k] = fNB[k]; }
  }
}

// ---------------- Kernel 3: projection + LayerNorm + ReLU + residual -------
// 128 threads; thread owns channels (t, t+128) x 32 n -> each broadcast ht
// read feeds 2 channels' FMAs. LDS overlay ht/yt (36 KB).
__global__ __launch_bounds__(128) void k_out(const __hip_bfloat16* __restrict__ hcat,
                                             const float* __restrict__ Wp,
                                             const float* __restrict__ bp,
                                             const float* __restrict__ gamma,
                                             const float* __restrict__ beta,
                                             const float* __restrict__ x,
                                             float* __restrict__ out) {
  __shared__ __align__(16) float smem[C_ * 36];   // overlaid ht / yt
  __shared__ float2 stats[NT3];
  float (*ht)[36]  = (float(*)[36])smem;          // [256][36] cc-major
  float (*yt)[260] = (float(*)[260])smem;         // [32][260] n-major
  const int bid = blockIdx.x;
  const int nb  = bid & 255;           // N/NT3 = 256
  const int b   = bid >> 8;
  const int t   = threadIdx.x;         // 0..127
  const int lane = t & 63;
  const int wv   = t >> 6;
  const int n0  = nb * NT3;
  const int ch0 = t, ch1 = t + 128;

  const __hip_bfloat16* hs0 = hcat + ((size_t)b * N_ + n0) * C_ + ch0;
  const __hip_bfloat16* hs1 = hcat + ((size_t)b * N_ + n0) * C_ + ch1;
#pragma unroll
  for (int s = 0; s < NT3; ++s) {
    ht[ch0][s] = __bfloat162float(hs0[(size_t)s * C_]);
    ht[ch1][s] = __bfloat162float(hs1[(size_t)s * C_]);
  }
  v2f acc0[16], acc1[16];
  const float b0 = bp[ch0], b1 = bp[ch1];
#pragma unroll
  for (int j = 0; j < 16; ++j) { acc0[j] = mkv2(b0, b0); acc1[j] = mkv2(b1, b1); }
  __syncthreads();

  const float4* w0 = (const float4*)(Wp + (size_t)ch0 * C_);
  const float4* w1 = (const float4*)(Wp + (size_t)ch1 * C_);
#pragma unroll 2
  for (int c4 = 0; c4 < 64; ++c4) {
    float4 wa = w0[c4], wb = w1[c4];
    float wq0[4] = {wa.x, wa.y, wa.z, wa.w};
    float wq1[4] = {wb.x, wb.y, wb.z, wb.w};
#pragma unroll
    for (int q = 0; q < 4; ++q) {
      v2f wv0 = mkv2(wq0[q], wq0[q]), wv1 = mkv2(wq1[q], wq1[q]);
      const float4* hr = (const float4*)&ht[c4 * 4 + q][0];
#pragma unroll
      for (int j4 = 0; j4 < 8; ++j4) {
        float4 h = hr[j4];
        v2f hx = mkv2(h.x, h.y), hy = mkv2(h.z, h.w);
        acc0[j4*2+0] = __builtin_elementwise_fma(wv0, hx, acc0[j4*2+0]);
        acc0[j4*2+1] = __builtin_elementwise_fma(wv0, hy, acc0[j4*2+1]);
        acc1[j4*2+0] = __builtin_elementwise_fma(wv1, hx, acc1[j4*2+0]);
        acc1[j4*2+1] = __builtin_elementwise_fma(wv1, hy, acc1[j4*2+1]);
      }
    }
  }
  // LayerNorm over channels: transpose via LDS (overlaid), wave-reduce per n
  __syncthreads();   // all ht reads done before yt overwrites the buffer
#pragma unroll
  for (int j = 0; j < NT3; ++j) {
    yt[j][ch0] = acc0[j >> 1][j & 1];
    yt[j][ch1] = acc1[j >> 1][j & 1];
  }
  __syncthreads();
#pragma unroll
  for (int r = 0; r < 16; ++r) {
    const int n = wv * 16 + r;
    float v0 = yt[n][lane], v1 = yt[n][lane + 64];
    float v2 = yt[n][lane + 128], v3 = yt[n][lane + 192];
    float s = v0 + v1 + v2 + v3;
    float q = v0 * v0 + v1 * v1 + v2 * v2 + v3 * v3;
#pragma unroll
    for (int off = 32; off >= 1; off >>= 1) {
      s += __shfl_xor(s, off);
      q += __shfl_xor(q, off);
    }
    if (lane == 0) {
      float mu  = s * (1.0f / 256.0f);
      float var = q * (1.0f / 256.0f) - mu * mu;
      var = var < 0.f ? 0.f : var;
      stats[n] = make_float2(mu, rsqrtf(var + 1e-5f));
    }
  }
  __syncthreads();
  // epilogue: channel ch0
  {
    const float gm = gamma[ch0], be = beta[ch0];
    const float* xr   = x   + ((size_t)b * C_ + ch0) * N_ + n0;
    float*       orow = out + ((size_t)b * C_ + ch0) * N_ + n0;
#pragma unroll
    for (int j4 = 0; j4 < 8; ++j4) {
      float4 xv = *(const float4*)(xr + j4 * 4);
      float4 o;
      { float2 st = stats[j4*4+0]; float v = (acc0[j4*2+0].x - st.x) * st.y * gm + be; o.x = fmaxf(v,0.f) + xv.x; }
      { float2 st = stats[j4*4+1]; float v = (acc0[j4*2+0].y - st.x) * st.y * gm + be; o.y = fmaxf(v,0.f) + xv.y; }
      { float2 st = stats[j4*4+2]; float v = (acc0[j4*2+1].x - st.x) * st.y * gm + be; o.z = fmaxf(v,0.f) + xv.z; }
      { float2 st = stats[j4*4+3]; float v = (acc0[j4*2+1].y - st.x) * st.y * gm + be; o.w = fmaxf(v,0.f) + xv.w; }
      *(float4*)(orow + j4 * 4) = o;
    }
  }
  // epilogue: channel ch1
  {
    const float gm = gamma[ch1], be = beta[ch1];
    const float* xr   = x   + ((size_t)b * C_ + ch1) * N_ + n0;
    float*       orow = out + ((size_t)b * C_ + ch1) * N_ + n0;
#pragma unroll
    for (int j4 = 0; j4 < 8; ++j4) {
      float4 xv = *(const float4*)(xr + j4 * 4);
      float4 o;
      { float2 st = stats[j4*4+0]; float v = (acc1[j4*2+0].x - st.x) * st.y * gm + be; o.x = fmaxf(v,0.f) + xv.x; }
      { float2 st = stats[j4*4+1]; float v = (acc1[j4*2+0].y - st.x) * st.y * gm + be; o.y = fmaxf(v,0.f) + xv.y; }
      { float2 st = stats[j4*4+2]; float v = (acc1[j4*2+1].x - st.x) * st.y * gm + be; o.z = fmaxf(v,0.f) + xv.z; }
      { float2 st = stats[j4*4+3]; float v = (acc1[j4*2+1].y - st.x) * st.y * gm + be; o.w = fmaxf(v,0.f) + xv.w; }
      *(float4*)(orow + j4 * 4) = o;
    }
  }
}

// ---------------------------------------------------------------------------
extern "C" void kernel_launch(void* const* d_in, const int* in_sizes, int n_in,
                              void* d_out, int out_size, void* d_ws, size_t ws_size,
                              hipStream_t stream) {
  const float* x      = (const float*)d_in[0];
  const float* W_ih   = (const float*)d_in[1];
  const float* W_hh   = (const float*)d_in[2];
  const float* b_ih   = (const float*)d_in[3];
  const float* b_hh   = (const float*)d_in[4];
  const float* W_proj = (const float*)d_in[5];
  const float* b_proj = (const float*)d_in[6];
  const float* gamma  = (const float*)d_in[7];
  const float* beta   = (const float*)d_in[8];
  float* out = (float*)d_out;

  const size_t preElems = (size_t)B_ * G_ * N_ * TH_;   // 50,331,648 bf16
  __hip_bfloat16* pre  = (__hip_bfloat16*)d_ws;
  __hip_bfloat16* hcat = pre + preElems;                // +33.5 MB, total 128 MiB

  k_pre<<<dim3(B_ * G_ * (N_ / NT1)), dim3(192), 0, stream>>>(x, W_ih, b_ih, pre);
  k_scan<<<dim3(B_ * G_ * NCHUNKS), dim3(64), 0, stream>>>(pre, W_hh, b_hh, hcat);
  k_out<<<dim3(B_ * (N_ / NT3)), dim3(128), 0, stream>>>(hcat, W_proj, b_proj,
                                                         gamma, beta, x, out);
}

// Round 5
// 481.321 us; speedup vs baseline: 1.3199x; 1.3199x over previous
//
#include <hip/hip_runtime.h>
#include <hip/hip_bf16.h>

// Problem constants
static constexpr int B_   = 8;
static constexpr int C_   = 256;
static constexpr int N_   = 8192;
static constexpr int G_   = 4;
static constexpr int GS_  = 64;   // group size (= H)
static constexpr int TH_  = 192;  // 3*H
static constexpr int NT1  = 16;   // n-tile for k_pre
static constexpr int NT3  = 32;   // n-tile for k_out

// Chunked-warm-up scan parallelization:
static constexpr int CHUNK = 256;        // steps written per workgroup
static constexpr int WARM  = 128;        // warm-up steps
static constexpr int NCHUNKS = N_ / CHUNK;  // 32

typedef float v2f __attribute__((ext_vector_type(2)));
__device__ __forceinline__ v2f mkv2(float a, float b) { v2f r; r.x = a; r.y = b; return r; }

__device__ __forceinline__ float fsigmoid(float x) {
  return __builtin_amdgcn_rcpf(1.0f + __expf(-x));
}
__device__ __forceinline__ float ftanh(float x) {
  float e = __expf(2.0f * x);                       // inf-safe: rcp(inf)=0
  return 1.0f - 2.0f * __builtin_amdgcn_rcpf(e + 1.0f);
}
__device__ __forceinline__ float bf16tof(unsigned short u) {
  return __uint_as_float(((unsigned int)u) << 16);
}

// ---------------- Kernel 1: input-gate precompute (R2 version) -------------
// pre[b][g][n][k] = sum_i x[b, g*64+i, n] * W_ih[g][k][i] + b_ih[g][k]  (bf16)
__global__ __launch_bounds__(192) void k_pre(const float* __restrict__ x,
                                             const float* __restrict__ W_ih,
                                             const float* __restrict__ b_ih,
                                             __hip_bfloat16* __restrict__ pre) {
  __shared__ __align__(16) float xt[GS_][NT1];
  const int bid = blockIdx.x;
  const int nb  = bid & 511;            // N/NT1 = 512
  const int bg  = bid >> 9;             // 0..31
  const int g   = bg & 3, b = bg >> 2;
  const int t   = threadIdx.x;          // 0..191 = gate row k
  const int n0  = nb * NT1;

  // stage x tile [64 i][16 n]
  for (int idx = t; idx < GS_ * NT1; idx += 192) {
    int i = idx >> 4, j = idx & 15;
    xt[i][j] = x[((size_t)(b * C_ + g * GS_ + i)) * N_ + n0 + j];
  }
  // W_ih row -> 64 regs
  float w[GS_];
  const float4* wp = (const float4*)(W_ih + ((size_t)g * TH_ + t) * GS_);
#pragma unroll
  for (int i4 = 0; i4 < 16; ++i4) {
    float4 v = wp[i4];
    w[i4 * 4 + 0] = v.x; w[i4 * 4 + 1] = v.y;
    w[i4 * 4 + 2] = v.z; w[i4 * 4 + 3] = v.w;
  }
  v2f acc2[8];
  const float bi = b_ih[g * TH_ + t];
#pragma unroll
  for (int j = 0; j < 8; ++j) acc2[j] = mkv2(bi, bi);
  __syncthreads();

#pragma unroll
  for (int i = 0; i < GS_; ++i) {
    const float4* xr = (const float4*)&xt[i][0];
    float4 a = xr[0], bq = xr[1], cq = xr[2], dq = xr[3];
    v2f wv = mkv2(w[i], w[i]);
    acc2[0] = __builtin_elementwise_fma(wv, mkv2(a.x,  a.y),  acc2[0]);
    acc2[1] = __builtin_elementwise_fma(wv, mkv2(a.z,  a.w),  acc2[1]);
    acc2[2] = __builtin_elementwise_fma(wv, mkv2(bq.x, bq.y), acc2[2]);
    acc2[3] = __builtin_elementwise_fma(wv, mkv2(bq.z, bq.w), acc2[3]);
    acc2[4] = __builtin_elementwise_fma(wv, mkv2(cq.x, cq.y), acc2[4]);
    acc2[5] = __builtin_elementwise_fma(wv, mkv2(cq.z, cq.w), acc2[5]);
    acc2[6] = __builtin_elementwise_fma(wv, mkv2(dq.x, dq.y), acc2[6]);
    acc2[7] = __builtin_elementwise_fma(wv, mkv2(dq.z, dq.w), acc2[7]);
  }
  __hip_bfloat16* po = pre + ((size_t)bg * N_ + n0) * TH_ + t;
#pragma unroll
  for (int j = 0; j < NT1; ++j)
    po[(size_t)j * TH_] = __float2bfloat16(acc2[j >> 1][j & 1]);
}

// ---------------- Kernel 2: sequential GRU scan (chunked warm-up) ----------
// ONE 64-lane wave per (bg, chunk): lane u owns unit u and all 3 gate rows.
// amdgpu_waves_per_eu(1,1): full 512-VGPR budget -> W_hh rows STAY resident
// (R3's allocator rematerialized them into the loop at VGPR_Count=124).
__global__ __launch_bounds__(64)
__attribute__((amdgpu_waves_per_eu(1, 1)))
void k_scan(const __hip_bfloat16* __restrict__ pre,
            const float* __restrict__ W_hh,
            const float* __restrict__ b_hh,
            __hip_bfloat16* __restrict__ hcat) {
  __shared__ __align__(16) float hbuf[GS_];
  const int bid = blockIdx.x;
  const int p   = bid & (NCHUNKS - 1);
  const int bg  = bid >> 5;
  const int g   = bg & 3, b = bg >> 2;
  const int u   = threadIdx.x;          // 0..63 = hidden unit

  const int n_lo    = p * CHUNK;
  const int n_end   = n_lo + CHUNK;
  const int n_start = (n_lo >= WARM) ? (n_lo - WARM) : 0;

  // 3 W_hh rows -> 96 v2f (192 VGPRs), resident under waves_per_eu(1,1)
  v2f wR[32], wZ[32], wN[32];
  const float4* wpR = (const float4*)(W_hh + ((size_t)g * TH_ + u) * GS_);
  const float4* wpZ = (const float4*)(W_hh + ((size_t)g * TH_ + 64 + u) * GS_);
  const float4* wpN = (const float4*)(W_hh + ((size_t)g * TH_ + 128 + u) * GS_);
#pragma unroll
  for (int i4 = 0; i4 < 16; ++i4) {
    float4 v = wpR[i4]; wR[2*i4] = mkv2(v.x, v.y); wR[2*i4+1] = mkv2(v.z, v.w);
    float4 y = wpZ[i4]; wZ[2*i4] = mkv2(y.x, y.y); wZ[2*i4+1] = mkv2(y.z, y.w);
    float4 q = wpN[i4]; wN[2*i4] = mkv2(q.x, q.y); wN[2*i4+1] = mkv2(q.z, q.w);
  }
  const float bR = b_hh[g * TH_ + u];
  const float bZ = b_hh[g * TH_ + 64 + u];
  const float bN = b_hh[g * TH_ + 128 + u];

  const unsigned short* pb = (const unsigned short*)(pre + (size_t)bg * N_ * TH_);
  __hip_bfloat16* ho = hcat + (size_t)b * N_ * C_ + g * GS_ + u;

  float hcur = 0.0f;
  hbuf[u] = 0.0f;

  // 4-step prefetch blocks, explicit A/B buffers (static indexing only)
  const int c0 = n_start >> 2, c1 = n_end >> 2;
  unsigned short fRA[4], fZA[4], fNA[4], fRB[4], fZB[4], fNB[4];
#pragma unroll
  for (int k = 0; k < 4; ++k) {
    size_t o = (size_t)(c0 * 4 + k) * TH_;
    fRA[k] = pb[o + u]; fZA[k] = pb[o + 64 + u]; fNA[k] = pb[o + 128 + u];
  }

  for (int nc = c0; nc < c1; ++nc) {
    if (nc + 1 < c1) {
#pragma unroll
      for (int k = 0; k < 4; ++k) {
        size_t o = (size_t)((nc + 1) * 4 + k) * TH_;
        fRB[k] = pb[o + u]; fZB[k] = pb[o + 64 + u]; fNB[k] = pb[o + 128 + u];
      }
    }
#pragma unroll
    for (int k = 0; k < 4; ++k) {
      const int n = nc * 4 + k;
      float pR = bf16tof(fRA[k]);
      float pZ = bf16tof(fZA[k]);
      float pN = bf16tof(fNA[k]);
      // 3 dots over h (broadcast from LDS), 6 independent packed chains
      v2f aR0 = mkv2(0.f, 0.f), aR1 = aR0, aZ0 = aR0, aZ1 = aR0, aN0 = aR0, aN1 = aR0;
#pragma unroll
      for (int i8 = 0; i8 < 8; ++i8) {
        float4 hA = *(const float4*)&hbuf[i8 * 8 + 0];
        float4 hB = *(const float4*)&hbuf[i8 * 8 + 4];
        v2f h0 = mkv2(hA.x, hA.y), h1 = mkv2(hA.z, hA.w);
        v2f h2 = mkv2(hB.x, hB.y), h3 = mkv2(hB.z, hB.w);
        aR0 = __builtin_elementwise_fma(wR[4*i8+0], h0, aR0);
        aR1 = __builtin_elementwise_fma(wR[4*i8+1], h1, aR1);
        aR0 = __builtin_elementwise_fma(wR[4*i8+2], h2, aR0);
        aR1 = __builtin_elementwise_fma(wR[4*i8+3], h3, aR1);
        aZ0 = __builtin_elementwise_fma(wZ[4*i8+0], h0, aZ0);
        aZ1 = __builtin_elementwise_fma(wZ[4*i8+1], h1, aZ1);
        aZ0 = __builtin_elementwise_fma(wZ[4*i8+2], h2, aZ0);
        aZ1 = __builtin_elementwise_fma(wZ[4*i8+3], h3, aZ1);
        aN0 = __builtin_elementwise_fma(wN[4*i8+0], h0, aN0);
        aN1 = __builtin_elementwise_fma(wN[4*i8+1], h1, aN1);
        aN0 = __builtin_elementwise_fma(wN[4*i8+2], h2, aN0);
        aN1 = __builtin_elementwise_fma(wN[4*i8+3], h3, aN1);
      }
      v2f sR = aR0 + aR1, sZ = aZ0 + aZ1, sN = aN0 + aN1;
      float r  = fsigmoid(sR.x + sR.y + bR + pR);
      float z  = fsigmoid(sZ.x + sZ.y + bZ + pZ);
      float gN = sN.x + sN.y + bN;
      float nn = ftanh(fmaf(r, gN, pN));
      float hnew = fmaf(z, hcur - nn, nn);  // (1-z)*n + z*h
      hcur = hnew;
      hbuf[u] = hnew;                       // visible next step (same wave)
      if (n >= n_lo) ho[(size_t)n * C_] = __float2bfloat16(hnew);
    }
#pragma unroll
    for (int k = 0; k < 4; ++k) { fRA[k] = fRB[k]; fZA[k] = fZB[k]; fNA[k] = fNB[k]; }
  }
}

// ---------------- Kernel 3: projection + LayerNorm + ReLU + residual -------
// (R2 version: 256 threads, LDS overlay ht/yt 36 KB -> 4 WG/CU)
__global__ __launch_bounds__(256) void k_out(const __hip_bfloat16* __restrict__ hcat,
                                             const float* __restrict__ Wp,
                                             const float* __restrict__ bp,
                                             const float* __restrict__ gamma,
                                             const float* __restrict__ beta,
                                             const float* __restrict__ x,
                                             float* __restrict__ out) {
  __shared__ __align__(16) float smem[C_ * 36];   // 9216 floats, overlaid
  __shared__ float2 stats[NT3];
  float (*ht)[36]  = (float(*)[36])smem;          // cc-major, padded
  float (*yt)[260] = (float(*)[260])smem;         // n-major for LN reduce
  const int bid = blockIdx.x;
  const int nb  = bid & 255;           // N/NT3 = 256
  const int b   = bid >> 8;
  const int t   = threadIdx.x;         // = output channel c
  const int lane = t & 63;
  const int wv   = t >> 6;
  const int n0  = nb * NT3;

  // stage hcat tile: ht[cc][n]
  const __hip_bfloat16* hsrc = hcat + ((size_t)b * N_ + n0) * C_ + t;
#pragma unroll
  for (int s = 0; s < NT3; ++s)
    ht[t][s] = __bfloat162float(hsrc[(size_t)s * C_]);

  v2f acc2[16];
  const float bpv = bp[t];
#pragma unroll
  for (int j = 0; j < 16; ++j) acc2[j] = mkv2(bpv, bpv);
  __syncthreads();

  const float4* wrow = (const float4*)(Wp + (size_t)t * C_);
#pragma unroll 2
  for (int c4 = 0; c4 < 64; ++c4) {
    float4 w4 = wrow[c4];
    float wq[4] = {w4.x, w4.y, w4.z, w4.w};
#pragma unroll
    for (int q = 0; q < 4; ++q) {
      v2f wqv = mkv2(wq[q], wq[q]);
      const float4* hr = (const float4*)&ht[c4 * 4 + q][0];
#pragma unroll
      for (int j4 = 0; j4 < 8; ++j4) {
        float4 h = hr[j4];
        acc2[j4 * 2 + 0] = __builtin_elementwise_fma(wqv, mkv2(h.x, h.y), acc2[j4 * 2 + 0]);
        acc2[j4 * 2 + 1] = __builtin_elementwise_fma(wqv, mkv2(h.z, h.w), acc2[j4 * 2 + 1]);
      }
    }
  }
  // LayerNorm over channels: transpose via LDS (overlaid!), wave-reduce per n
  __syncthreads();   // all ht reads done before yt overwrites the buffer
#pragma unroll
  for (int j = 0; j < NT3; ++j) yt[j][t] = acc2[j >> 1][j & 1];
  __syncthreads();
#pragma unroll
  for (int r = 0; r < 8; ++r) {
    const int n = wv * 8 + r;
    float v0 = yt[n][lane], v1 = yt[n][lane + 64];
    float v2 = yt[n][lane + 128], v3 = yt[n][lane + 192];
    float s = v0 + v1 + v2 + v3;
    float q = v0 * v0 + v1 * v1 + v2 * v2 + v3 * v3;
#pragma unroll
    for (int off = 32; off >= 1; off >>= 1) {
      s += __shfl_xor(s, off);
      q += __shfl_xor(q, off);
    }
    if (lane == 0) {
      float mu  = s * (1.0f / 256.0f);
      float var = q * (1.0f / 256.0f) - mu * mu;
      var = var < 0.f ? 0.f : var;
      stats[n] = make_float2(mu, rsqrtf(var + 1e-5f));
    }
  }
  __syncthreads();
  const float gm = gamma[t], be = beta[t];
  const float* xr   = x   + ((size_t)b * C_ + t) * N_ + n0;
  float*       orow = out + ((size_t)b * C_ + t) * N_ + n0;
#pragma unroll
  for (int j4 = 0; j4 < 8; ++j4) {
    float4 xv = *(const float4*)(xr + j4 * 4);
    float4 o;
    { float2 st = stats[j4 * 4 + 0];
      float v = (acc2[j4 * 2 + 0].x - st.x) * st.y * gm + be;
      o.x = fmaxf(v, 0.f) + xv.x; }
    { float2 st = stats[j4 * 4 + 1];
      float v = (acc2[j4 * 2 + 0].y - st.x) * st.y * gm + be;
      o.y = fmaxf(v, 0.f) + xv.y; }
    { float2 st = stats[j4 * 4 + 2];
      float v = (acc2[j4 * 2 + 1].x - st.x) * st.y * gm + be;
      o.z = fmaxf(v, 0.f) + xv.z; }
    { float2 st = stats[j4 * 4 + 3];
      float v = (acc2[j4 * 2 + 1].y - st.x) * st.y * gm + be;
      o.w = fmaxf(v, 0.f) + xv.w; }
    *(float4*)(orow + j4 * 4) = o;
  }
}

// ---------------------------------------------------------------------------
extern "C" void kernel_launch(void* const* d_in, const int* in_sizes, int n_in,
                              void* d_out, int out_size, void* d_ws, size_t ws_size,
                              hipStream_t stream) {
  const float* x      = (const float*)d_in[0];
  const float* W_ih   = (const float*)d_in[1];
  const float* W_hh   = (const float*)d_in[2];
  const float* b_ih   = (const float*)d_in[3];
  const float* b_hh   = (const float*)d_in[4];
  const float* W_proj = (const float*)d_in[5];
  const float* b_proj = (const float*)d_in[6];
  const float* gamma  = (const float*)d_in[7];
  const float* beta   = (const float*)d_in[8];
  float* out = (float*)d_out;

  const size_t preElems = (size_t)B_ * G_ * N_ * TH_;   // 50,331,648 bf16
  __hip_bfloat16* pre  = (__hip_bfloat16*)d_ws;
  __hip_bfloat16* hcat = pre + preElems;                // +33.5 MB, total 128 MiB

  k_pre<<<dim3(B_ * G_ * (N_ / NT1)), dim3(192), 0, stream>>>(x, W_ih, b_ih, pre);
  k_scan<<<dim3(B_ * G_ * NCHUNKS), dim3(64), 0, stream>>>(pre, W_hh, b_hh, hcat);
  k_out<<<dim3(B_ * (N_ / NT3)), dim3(256), 0, stream>>>(hcat, W_proj, b_proj,
                                                         gamma, beta, x, out);
}

// Round 6
// 479.481 us; speedup vs baseline: 1.3250x; 1.0038x over previous
//
#include <hip/hip_runtime.h>
#include <hip/hip_bf16.h>

// Problem constants
static constexpr int B_   = 8;
static constexpr int C_   = 256;
static constexpr int N_   = 8192;
static constexpr int G_   = 4;
static constexpr int GS_  = 64;   // group size (= H)
static constexpr int TH_  = 192;  // 3*H
static constexpr int NT1  = 16;   // n-tile for k_pre
static constexpr int NT3  = 32;   // n-tile for k_out

// Chunked-warm-up scan parallelization:
static constexpr int CHUNK = 256;        // steps written per workgroup
static constexpr int WARM  = 128;        // warm-up steps
static constexpr int NCHUNKS = N_ / CHUNK;  // 32

typedef float v2f __attribute__((ext_vector_type(2)));
__device__ __forceinline__ v2f mkv2(float a, float b) { v2f r; r.x = a; r.y = b; return r; }

// Anti-rematerialization: route a 64-bit value through an asm def. Inline asm
// is not rematerializable, so the register allocator must keep the value
// live in VGPRs (R3/R4: plain loads got sunk into the scan loop, VGPR=124/132).
__device__ __forceinline__ void keep(v2f& v) {
  double d = __builtin_bit_cast(double, v);
  asm volatile("" : "+v"(d));
  v = __builtin_bit_cast(v2f, d);
}

__device__ __forceinline__ float fsigmoid(float x) {
  return __builtin_amdgcn_rcpf(1.0f + __expf(-x));
}
__device__ __forceinline__ float ftanh(float x) {
  float e = __expf(2.0f * x);                       // inf-safe: rcp(inf)=0
  return 1.0f - 2.0f * __builtin_amdgcn_rcpf(e + 1.0f);
}
__device__ __forceinline__ float bf16tof(unsigned short u) {
  return __uint_as_float(((unsigned int)u) << 16);
}

// ---------------- Kernel 1: input-gate precompute (R2 version) -------------
// pre[b][g][n][k] = sum_i x[b, g*64+i, n] * W_ih[g][k][i] + b_ih[g][k]  (bf16)
__global__ __launch_bounds__(192) void k_pre(const float* __restrict__ x,
                                             const float* __restrict__ W_ih,
                                             const float* __restrict__ b_ih,
                                             __hip_bfloat16* __restrict__ pre) {
  __shared__ __align__(16) float xt[GS_][NT1];
  const int bid = blockIdx.x;
  const int nb  = bid & 511;            // N/NT1 = 512
  const int bg  = bid >> 9;             // 0..31
  const int g   = bg & 3, b = bg >> 2;
  const int t   = threadIdx.x;          // 0..191 = gate row k
  const int n0  = nb * NT1;

  // stage x tile [64 i][16 n]
  for (int idx = t; idx < GS_ * NT1; idx += 192) {
    int i = idx >> 4, j = idx & 15;
    xt[i][j] = x[((size_t)(b * C_ + g * GS_ + i)) * N_ + n0 + j];
  }
  // W_ih row -> 64 regs
  float w[GS_];
  const float4* wp = (const float4*)(W_ih + ((size_t)g * TH_ + t) * GS_);
#pragma unroll
  for (int i4 = 0; i4 < 16; ++i4) {
    float4 v = wp[i4];
    w[i4 * 4 + 0] = v.x; w[i4 * 4 + 1] = v.y;
    w[i4 * 4 + 2] = v.z; w[i4 * 4 + 3] = v.w;
  }
  v2f acc2[8];
  const float bi = b_ih[g * TH_ + t];
#pragma unroll
  for (int j = 0; j < 8; ++j) acc2[j] = mkv2(bi, bi);
  __syncthreads();

#pragma unroll
  for (int i = 0; i < GS_; ++i) {
    const float4* xr = (const float4*)&xt[i][0];
    float4 a = xr[0], bq = xr[1], cq = xr[2], dq = xr[3];
    v2f wv = mkv2(w[i], w[i]);
    acc2[0] = __builtin_elementwise_fma(wv, mkv2(a.x,  a.y),  acc2[0]);
    acc2[1] = __builtin_elementwise_fma(wv, mkv2(a.z,  a.w),  acc2[1]);
    acc2[2] = __builtin_elementwise_fma(wv, mkv2(bq.x, bq.y), acc2[2]);
    acc2[3] = __builtin_elementwise_fma(wv, mkv2(bq.z, bq.w), acc2[3]);
    acc2[4] = __builtin_elementwise_fma(wv, mkv2(cq.x, cq.y), acc2[4]);
    acc2[5] = __builtin_elementwise_fma(wv, mkv2(cq.z, cq.w), acc2[5]);
    acc2[6] = __builtin_elementwise_fma(wv, mkv2(dq.x, dq.y), acc2[6]);
    acc2[7] = __builtin_elementwise_fma(wv, mkv2(dq.z, dq.w), acc2[7]);
  }
  __hip_bfloat16* po = pre + ((size_t)bg * N_ + n0) * TH_ + t;
#pragma unroll
  for (int j = 0; j < NT1; ++j)
    po[(size_t)j * TH_] = __float2bfloat16(acc2[j >> 1][j & 1]);
}

// ---------------- Kernel 2: sequential GRU scan (chunked warm-up) ----------
// ONE 64-lane wave per (bg, chunk): lane u owns unit u and all 3 gate rows.
// waves_per_eu(1,1) gives the 512-VGPR budget; keep() pins the 96 v2f weights
// in registers (asm defs are non-rematerializable).
__global__ __launch_bounds__(64)
__attribute__((amdgpu_waves_per_eu(1, 1)))
void k_scan(const __hip_bfloat16* __restrict__ pre,
            const float* __restrict__ W_hh,
            const float* __restrict__ b_hh,
            __hip_bfloat16* __restrict__ hcat) {
  __shared__ __align__(16) float hbuf[GS_];
  const int bid = blockIdx.x;
  const int p   = bid & (NCHUNKS - 1);
  const int bg  = bid >> 5;
  const int g   = bg & 3, b = bg >> 2;
  const int u   = threadIdx.x;          // 0..63 = hidden unit

  const int n_lo    = p * CHUNK;
  const int n_end   = n_lo + CHUNK;
  const int n_start = (n_lo >= WARM) ? (n_lo - WARM) : 0;

  // 3 W_hh rows -> 96 v2f (192 VGPRs), pinned resident via keep()
  v2f wR[32], wZ[32], wN[32];
  const float4* wpR = (const float4*)(W_hh + ((size_t)g * TH_ + u) * GS_);
  const float4* wpZ = (const float4*)(W_hh + ((size_t)g * TH_ + 64 + u) * GS_);
  const float4* wpN = (const float4*)(W_hh + ((size_t)g * TH_ + 128 + u) * GS_);
#pragma unroll
  for (int i4 = 0; i4 < 16; ++i4) {
    float4 v = wpR[i4]; wR[2*i4] = mkv2(v.x, v.y); wR[2*i4+1] = mkv2(v.z, v.w);
    float4 y = wpZ[i4]; wZ[2*i4] = mkv2(y.x, y.y); wZ[2*i4+1] = mkv2(y.z, y.w);
    float4 q = wpN[i4]; wN[2*i4] = mkv2(q.x, q.y); wN[2*i4+1] = mkv2(q.z, q.w);
  }
#pragma unroll
  for (int i = 0; i < 32; ++i) { keep(wR[i]); keep(wZ[i]); keep(wN[i]); }
  const float bR = b_hh[g * TH_ + u];
  const float bZ = b_hh[g * TH_ + 64 + u];
  const float bN = b_hh[g * TH_ + 128 + u];

  const unsigned short* pb = (const unsigned short*)(pre + (size_t)bg * N_ * TH_);
  __hip_bfloat16* ho = hcat + (size_t)b * N_ * C_ + g * GS_ + u;

  float hcur = 0.0f;
  hbuf[u] = 0.0f;

  // 4-step prefetch blocks, explicit A/B buffers (static indexing only)
  const int c0 = n_start >> 2, c1 = n_end >> 2;
  unsigned short fRA[4], fZA[4], fNA[4], fRB[4], fZB[4], fNB[4];
#pragma unroll
  for (int k = 0; k < 4; ++k) {
    size_t o = (size_t)(c0 * 4 + k) * TH_;
    fRA[k] = pb[o + u]; fZA[k] = pb[o + 64 + u]; fNA[k] = pb[o + 128 + u];
  }

  for (int nc = c0; nc < c1; ++nc) {
    if (nc + 1 < c1) {
#pragma unroll
      for (int k = 0; k < 4; ++k) {
        size_t o = (size_t)((nc + 1) * 4 + k) * TH_;
        fRB[k] = pb[o + u]; fZB[k] = pb[o + 64 + u]; fNB[k] = pb[o + 128 + u];
      }
    }
#pragma unroll
    for (int k = 0; k < 4; ++k) {
      const int n = nc * 4 + k;
      float pR = bf16tof(fRA[k]);
      float pZ = bf16tof(fZA[k]);
      float pN = bf16tof(fNA[k]);
      // 3 dots over h (broadcast from LDS), 6 independent packed chains
      v2f aR0 = mkv2(0.f, 0.f), aR1 = aR0, aZ0 = aR0, aZ1 = aR0, aN0 = aR0, aN1 = aR0;
#pragma unroll
      for (int i8 = 0; i8 < 8; ++i8) {
        float4 hA = *(const float4*)&hbuf[i8 * 8 + 0];
        float4 hB = *(const float4*)&hbuf[i8 * 8 + 4];
        v2f h0 = mkv2(hA.x, hA.y), h1 = mkv2(hA.z, hA.w);
        v2f h2 = mkv2(hB.x, hB.y), h3 = mkv2(hB.z, hB.w);
        aR0 = __builtin_elementwise_fma(wR[4*i8+0], h0, aR0);
        aR1 = __builtin_elementwise_fma(wR[4*i8+1], h1, aR1);
        aR0 = __builtin_elementwise_fma(wR[4*i8+2], h2, aR0);
        aR1 = __builtin_elementwise_fma(wR[4*i8+3], h3, aR1);
        aZ0 = __builtin_elementwise_fma(wZ[4*i8+0], h0, aZ0);
        aZ1 = __builtin_elementwise_fma(wZ[4*i8+1], h1, aZ1);
        aZ0 = __builtin_elementwise_fma(wZ[4*i8+2], h2, aZ0);
        aZ1 = __builtin_elementwise_fma(wZ[4*i8+3], h3, aZ1);
        aN0 = __builtin_elementwise_fma(wN[4*i8+0], h0, aN0);
        aN1 = __builtin_elementwise_fma(wN[4*i8+1], h1, aN1);
        aN0 = __builtin_elementwise_fma(wN[4*i8+2], h2, aN0);
        aN1 = __builtin_elementwise_fma(wN[4*i8+3], h3, aN1);
      }
      v2f sR = aR0 + aR1, sZ = aZ0 + aZ1, sN = aN0 + aN1;
      float r  = fsigmoid(sR.x + sR.y + bR + pR);
      float z  = fsigmoid(sZ.x + sZ.y + bZ + pZ);
      float gN = sN.x + sN.y + bN;
      float nn = ftanh(fmaf(r, gN, pN));
      float hnew = fmaf(z, hcur - nn, nn);  // (1-z)*n + z*h
      hcur = hnew;
      hbuf[u] = hnew;                       // visible next step (same wave)
      if (n >= n_lo) ho[(size_t)n * C_] = __float2bfloat16(hnew);
    }
#pragma unroll
    for (int k = 0; k < 4; ++k) { fRA[k] = fRB[k]; fZA[k] = fZB[k]; fNA[k] = fNB[k]; }
  }
}

// ---------------- Kernel 3: projection + LayerNorm + ReLU + residual -------
// (R2 version: 256 threads, LDS overlay ht/yt 36 KB -> 4 WG/CU)
__global__ __launch_bounds__(256) void k_out(const __hip_bfloat16* __restrict__ hcat,
                                             const float* __restrict__ Wp,
                                             const float* __restrict__ bp,
                                             const float* __restrict__ gamma,
                                             const float* __restrict__ beta,
                                             const float* __restrict__ x,
                                             float* __restrict__ out) {
  __shared__ __align__(16) float smem[C_ * 36];   // 9216 floats, overlaid
  __shared__ float2 stats[NT3];
  float (*ht)[36]  = (float(*)[36])smem;          // cc-major, padded
  float (*yt)[260] = (float(*)[260])smem;         // n-major for LN reduce
  const int bid = blockIdx.x;
  const int nb  = bid & 255;           // N/NT3 = 256
  const int b   = bid >> 8;
  const int t   = threadIdx.x;         // = output channel c
  const int lane = t & 63;
  const int wv   = t >> 6;
  const int n0  = nb * NT3;

  // stage hcat tile: ht[cc][n]
  const __hip_bfloat16* hsrc = hcat + ((size_t)b * N_ + n0) * C_ + t;
#pragma unroll
  for (int s = 0; s < NT3; ++s)
    ht[t][s] = __bfloat162float(hsrc[(size_t)s * C_]);

  v2f acc2[16];
  const float bpv = bp[t];
#pragma unroll
  for (int j = 0; j < 16; ++j) acc2[j] = mkv2(bpv, bpv);
  __syncthreads();

  const float4* wrow = (const float4*)(Wp + (size_t)t * C_);
#pragma unroll 2
  for (int c4 = 0; c4 < 64; ++c4) {
    float4 w4 = wrow[c4];
    float wq[4] = {w4.x, w4.y, w4.z, w4.w};
#pragma unroll
    for (int q = 0; q < 4; ++q) {
      v2f wqv = mkv2(wq[q], wq[q]);
      const float4* hr = (const float4*)&ht[c4 * 4 + q][0];
#pragma unroll
      for (int j4 = 0; j4 < 8; ++j4) {
        float4 h = hr[j4];
        acc2[j4 * 2 + 0] = __builtin_elementwise_fma(wqv, mkv2(h.x, h.y), acc2[j4 * 2 + 0]);
        acc2[j4 * 2 + 1] = __builtin_elementwise_fma(wqv, mkv2(h.z, h.w), acc2[j4 * 2 + 1]);
      }
    }
  }
  // LayerNorm over channels: transpose via LDS (overlaid!), wave-reduce per n
  __syncthreads();   // all ht reads done before yt overwrites the buffer
#pragma unroll
  for (int j = 0; j < NT3; ++j) yt[j][t] = acc2[j >> 1][j & 1];
  __syncthreads();
#pragma unroll
  for (int r = 0; r < 8; ++r) {
    const int n = wv * 8 + r;
    float v0 = yt[n][lane], v1 = yt[n][lane + 64];
    float v2 = yt[n][lane + 128], v3 = yt[n][lane + 192];
    float s = v0 + v1 + v2 + v3;
    float q = v0 * v0 + v1 * v1 + v2 * v2 + v3 * v3;
#pragma unroll
    for (int off = 32; off >= 1; off >>= 1) {
      s += __shfl_xor(s, off);
      q += __shfl_xor(q, off);
    }
    if (lane == 0) {
      float mu  = s * (1.0f / 256.0f);
      float var = q * (1.0f / 256.0f) - mu * mu;
      var = var < 0.f ? 0.f : var;
      stats[n] = make_float2(mu, rsqrtf(var + 1e-5f));
    }
  }
  __syncthreads();
  const float gm = gamma[t], be = beta[t];
  const float* xr   = x   + ((size_t)b * C_ + t) * N_ + n0;
  float*       orow = out + ((size_t)b * C_ + t) * N_ + n0;
#pragma unroll
  for (int j4 = 0; j4 < 8; ++j4) {
    float4 xv = *(const float4*)(xr + j4 * 4);
    float4 o;
    { float2 st = stats[j4 * 4 + 0];
      float v = (acc2[j4 * 2 + 0].x - st.x) * st.y * gm + be;
      o.x = fmaxf(v, 0.f) + xv.x; }
    { float2 st = stats[j4 * 4 + 1];
      float v = (acc2[j4 * 2 + 0].y - st.x) * st.y * gm + be;
      o.y = fmaxf(v, 0.f) + xv.y; }
    { float2 st = stats[j4 * 4 + 2];
      float v = (acc2[j4 * 2 + 1].x - st.x) * st.y * gm + be;
      o.z = fmaxf(v, 0.f) + xv.z; }
    { float2 st = stats[j4 * 4 + 3];
      float v = (acc2[j4 * 2 + 1].y - st.x) * st.y * gm + be;
      o.w = fmaxf(v, 0.f) + xv.w; }
    *(float4*)(orow + j4 * 4) = o;
  }
}

// ---------------------------------------------------------------------------
extern "C" void kernel_launch(void* const* d_in, const int* in_sizes, int n_in,
                              void* d_out, int out_size, void* d_ws, size_t ws_size,
                              hipStream_t stream) {
  const float* x      = (const float*)d_in[0];
  const float* W_ih   = (const float*)d_in[1];
  const float* W_hh   = (const float*)d_in[2];
  const float* b_ih   = (const float*)d_in[3];
  const float* b_hh   = (const float*)d_in[4];
  const float* W_proj = (const float*)d_in[5];
  const float* b_proj = (const float*)d_in[6];
  const float* gamma  = (const float*)d_in[7];
  const float* beta   = (const float*)d_in[8];
  float* out = (float*)d_out;

  const size_t preElems = (size_t)B_ * G_ * N_ * TH_;   // 50,331,648 bf16
  __hip_bfloat16* pre  = (__hip_bfloat16*)d_ws;
  __hip_bfloat16* hcat = pre + preElems;                // +33.5 MB, total 128 MiB

  k_pre<<<dim3(B_ * G_ * (N_ / NT1)), dim3(192), 0, stream>>>(x, W_ih, b_ih, pre);
  k_scan<<<dim3(B_ * G_ * NCHUNKS), dim3(64), 0, stream>>>(pre, W_hh, b_hh, hcat);
  k_out<<<dim3(B_ * (N_ / NT3)), dim3(256), 0, stream>>>(hcat, W_proj, b_proj,
                                                         gamma, beta, x, out);
}

// Round 7
// 416.518 us; speedup vs baseline: 1.5253x; 1.1512x over previous
//
#include <hip/hip_runtime.h>
#include <hip/hip_bf16.h>

// Problem constants
static constexpr int B_   = 8;
static constexpr int C_   = 256;
static constexpr int N_   = 8192;
static constexpr int G_   = 4;
static constexpr int GS_  = 64;   // group size (= H)
static constexpr int TH_  = 192;  // 3*H
static constexpr int NT1  = 16;   // n-tile for k_pre
static constexpr int NT3  = 32;   // n-tile for k_out

// MFMA scan: 16 chains per wave, chunked warm-up
static constexpr int CHUNK = 32;         // steps written per chain
static constexpr int WARM  = 64;         // warm-up steps
static constexpr int ITS   = CHUNK + WARM;      // 96 iterations per wave
static constexpr int NCH_  = N_ / CHUNK;        // 256 chunks per (b,g)
static constexpr int WGRP_ = NCH_ / 16;         // 16 waves per (b,g)

typedef float v2f __attribute__((ext_vector_type(2)));
typedef __attribute__((ext_vector_type(8))) short short8;   // 8 bf16 (4 VGPRs)
typedef __attribute__((ext_vector_type(4))) float f32x4;    // MFMA acc
typedef __attribute__((ext_vector_type(2))) unsigned int u32x2;
typedef __attribute__((ext_vector_type(4))) unsigned int u32x4;

__device__ __forceinline__ v2f mkv2(float a, float b) { v2f r; r.x = a; r.y = b; return r; }

__device__ __forceinline__ float fsigmoid(float x) {
  return __builtin_amdgcn_rcpf(1.0f + __expf(-x));
}
__device__ __forceinline__ float ftanh(float x) {
  float e = __expf(2.0f * x);                       // inf-safe: rcp(inf)=0
  return 1.0f - 2.0f * __builtin_amdgcn_rcpf(e + 1.0f);
}
// RNE f32->bf16 pack, 2-in-1 (no builtin on gfx950; asm also blocks remat)
__device__ __forceinline__ unsigned cvtpk(float lo, float hi) {
  unsigned r;
  asm("v_cvt_pk_bf16_f32 %0, %1, %2" : "=v"(r) : "v"(lo), "v"(hi));
  return r;
}
__device__ __forceinline__ f32x4 unpack4(u32x2 p) {
  f32x4 r;
  r[0] = __uint_as_float(p.x << 16);
  r[1] = __uint_as_float(p.x & 0xffff0000u);
  r[2] = __uint_as_float(p.y << 16);
  r[3] = __uint_as_float(p.y & 0xffff0000u);
  return r;
}

// ---------------- Kernel 1: input-gate precompute --------------------------
// pre[b][g][n][k] = sum_i x[...]*W_ih + b_ih[k] + (k<128 ? b_hh[k] : 0)
// (r/z hh-biases folded; n-gate hh-bias must stay inside the r* multiply)
__global__ __launch_bounds__(192) void k_pre(const float* __restrict__ x,
                                             const float* __restrict__ W_ih,
                                             const float* __restrict__ b_ih,
                                             const float* __restrict__ b_hh,
                                             __hip_bfloat16* __restrict__ pre) {
  __shared__ __align__(16) float xt[GS_][NT1];
  const int bid = blockIdx.x;
  const int nb  = bid & 511;            // N/NT1 = 512
  const int bg  = bid >> 9;             // 0..31
  const int g   = bg & 3, b = bg >> 2;
  const int t   = threadIdx.x;          // 0..191 = gate row k
  const int n0  = nb * NT1;

  for (int idx = t; idx < GS_ * NT1; idx += 192) {
    int i = idx >> 4, j = idx & 15;
    xt[i][j] = x[((size_t)(b * C_ + g * GS_ + i)) * N_ + n0 + j];
  }
  float w[GS_];
  const float4* wp = (const float4*)(W_ih + ((size_t)g * TH_ + t) * GS_);
#pragma unroll
  for (int i4 = 0; i4 < 16; ++i4) {
    float4 v = wp[i4];
    w[i4 * 4 + 0] = v.x; w[i4 * 4 + 1] = v.y;
    w[i4 * 4 + 2] = v.z; w[i4 * 4 + 3] = v.w;
  }
  v2f acc2[8];
  const float bi = b_ih[g * TH_ + t] + ((t < 128) ? b_hh[g * TH_ + t] : 0.0f);
#pragma unroll
  for (int j = 0; j < 8; ++j) acc2[j] = mkv2(bi, bi);
  __syncthreads();

#pragma unroll
  for (int i = 0; i < GS_; ++i) {
    const float4* xr = (const float4*)&xt[i][0];
    float4 a = xr[0], bq = xr[1], cq = xr[2], dq = xr[3];
    v2f wv = mkv2(w[i], w[i]);
    acc2[0] = __builtin_elementwise_fma(wv, mkv2(a.x,  a.y),  acc2[0]);
    acc2[1] = __builtin_elementwise_fma(wv, mkv2(a.z,  a.w),  acc2[1]);
    acc2[2] = __builtin_elementwise_fma(wv, mkv2(bq.x, bq.y), acc2[2]);
    acc2[3] = __builtin_elementwise_fma(wv, mkv2(bq.z, bq.w), acc2[3]);
    acc2[4] = __builtin_elementwise_fma(wv, mkv2(cq.x, cq.y), acc2[4]);
    acc2[5] = __builtin_elementwise_fma(wv, mkv2(cq.z, cq.w), acc2[5]);
    acc2[6] = __builtin_elementwise_fma(wv, mkv2(dq.x, dq.y), acc2[6]);
    acc2[7] = __builtin_elementwise_fma(wv, mkv2(dq.z, dq.w), acc2[7]);
  }
  __hip_bfloat16* po = pre + ((size_t)bg * N_ + n0) * TH_ + t;
#pragma unroll
  for (int j = 0; j < NT1; ++j)
    po[(size_t)j * TH_] = __float2bfloat16(acc2[j >> 1][j & 1]);
}

// ---------------- Kernel 2: MFMA GRU scan ----------------------------------
// One wave per WG; 16 chains (chunks) per wave. Per step:
//   G[192x16] = W_hh x H  via 24 mfma_f32_16x16x32_bf16 (acc init = pre).
// W_hh lives in 96 VGPRs as bf16 A-frags (cvt_pk asm defs: not remat-able).
// h round-trips through a 2.5KB LDS H^T[chain][row] buffer, lane-local.
__global__ __launch_bounds__(64, 1)
void k_scan(const __hip_bfloat16* __restrict__ pre,
            const float* __restrict__ W_hh,
            const float* __restrict__ b_hh,
            __hip_bfloat16* __restrict__ hcat) {
  __shared__ __align__(16) unsigned short HT[16 * 80];  // [chain][80], rows 0..63 used
  const int bid = blockIdx.x;
  const int wg  = bid & (WGRP_ - 1);    // wave-group within bg (0..15)
  const int bg  = bid >> 4;
  const int g   = bg & 3, b = bg >> 2;
  const int l   = threadIdx.x;
  const int c   = l & 15;               // chain column
  const int q   = l >> 4;               // 0..3

  const int cg  = wg * 16 + c;          // global chunk id 0..255
  const int nlo = cg * CHUNK;
  const int n0  = (nlo >= WARM) ? (nlo - WARM) : 0;
  const int wst = nlo - n0;             // write-start iteration (0/32/64)

  // A fragments: a[t][kk] elem e = W_hh[g][16t + c][32kk + 8q + e] (bf16)
  short8 a[12][2];
#pragma unroll
  for (int t = 0; t < 12; ++t) {
#pragma unroll
    for (int kk = 0; kk < 2; ++kk) {
      const float* wr = W_hh + ((size_t)g * TH_ + 16 * t + c) * GS_ + 32 * kk + 8 * q;
      float4 w0 = *(const float4*)wr;
      float4 w1 = *(const float4*)(wr + 4);
      u32x4 pk;
      pk.x = cvtpk(w0.x, w0.y); pk.y = cvtpk(w0.z, w0.w);
      pk.z = cvtpk(w1.x, w1.y); pk.w = cvtpk(w1.z, w1.w);
      a[t][kk] = __builtin_bit_cast(short8, pk);
    }
  }
  // n-gate hh-bias: rows 128 + 16*t2 + 4q + j
  f32x4 bN[4];
#pragma unroll
  for (int t2 = 0; t2 < 4; ++t2) {
    float4 v = *(const float4*)(b_hh + (size_t)g * TH_ + 128 + 16 * t2 + 4 * q);
    bN[t2][0] = v.x; bN[t2][1] = v.y; bN[t2][2] = v.z; bN[t2][3] = v.w;
  }

  // zero H^T (this lane's write slots cover all rows of its chain)
  {
    u32x2 z2; z2.x = 0u; z2.y = 0u;
#pragma unroll
    for (int t2 = 0; t2 < 4; ++t2)
      *(u32x2*)((char*)HT + 160 * c + 32 * t2 + 8 * q) = z2;
  }

  // pre byte base for this lane: rows 16t+4q at chain cg, step n0
  const char* pbase = (const char*)pre + ((size_t)bg * N_ + n0) * (TH_ * 2) + 8 * q;
  char* hbase = (char*)hcat + (((size_t)b * N_ + n0) * C_ + g * 64 + 4 * q) * 2;

  u32x2 prA[12], prB[12];
#pragma unroll
  for (int t = 0; t < 12; ++t) prA[t] = *(const u32x2*)(pbase + 32 * t);

  f32x4 h[4];
#pragma unroll
  for (int t2 = 0; t2 < 4; ++t2) { h[t2][0] = 0.f; h[t2][1] = 0.f; h[t2][2] = 0.f; h[t2][3] = 0.f; }

#define SCAN_STEP(CUR, NXT, IT)                                                  \
  {                                                                              \
    const int it = (IT);                                                         \
    _Pragma("unroll")                                                            \
    for (int t = 0; t < 12; ++t)                                                 \
      NXT[t] = *(const u32x2*)(pbase + (size_t)(it + 1) * 384 + 32 * t);         \
    f32x4 acc[12];                                                               \
    f32x4 pN[4];                                                                 \
    _Pragma("unroll")                                                            \
    for (int t2 = 0; t2 < 4; ++t2) {                                             \
      acc[t2]     = unpack4(CUR[t2]);                                            \
      acc[t2 + 4] = unpack4(CUR[t2 + 4]);                                        \
      acc[t2 + 8] = bN[t2];                                                      \
      pN[t2]      = unpack4(CUR[t2 + 8]);                                        \
    }                                                                            \
    short8 bf0 = *(const short8*)((const char*)HT + 160 * c + 16 * q);           \
    short8 bf1 = *(const short8*)((const char*)HT + 160 * c + 16 * q + 64);      \
    _Pragma("unroll")                                                            \
    for (int t = 0; t < 12; ++t) {                                               \
      acc[t] = __builtin_amdgcn_mfma_f32_16x16x32_bf16(a[t][0], bf0, acc[t], 0, 0, 0); \
      acc[t] = __builtin_amdgcn_mfma_f32_16x16x32_bf16(a[t][1], bf1, acc[t], 0, 0, 0); \
    }                                                                            \
    unsigned pk0[4], pk1[4];                                                     \
    _Pragma("unroll")                                                            \
    for (int t2 = 0; t2 < 4; ++t2) {                                             \
      float hn[4];                                                               \
      _Pragma("unroll")                                                          \
      for (int j = 0; j < 4; ++j) {                                              \
        float r  = fsigmoid(acc[t2][j]);                                         \
        float zz = fsigmoid(acc[t2 + 4][j]);                                     \
        float nn = ftanh(fmaf(r, acc[t2 + 8][j], pN[t2][j]));                    \
        float hv = fmaf(zz, h[t2][j] - nn, nn);                                  \
        h[t2][j] = hv; hn[j] = hv;                                               \
      }                                                                          \
      pk0[t2] = cvtpk(hn[0], hn[1]);                                             \
      pk1[t2] = cvtpk(hn[2], hn[3]);                                             \
      u32x2 wv2; wv2.x = pk0[t2]; wv2.y = pk1[t2];                               \
      *(u32x2*)((char*)HT + 160 * c + 32 * t2 + 8 * q) = wv2;                    \
    }                                                                            \
    if (it >= wst && it < wst + CHUNK) {                                         \
      _Pragma("unroll")                                                          \
      for (int t2 = 0; t2 < 4; ++t2) {                                           \
        u32x2 sv; sv.x = pk0[t2]; sv.y = pk1[t2];                                \
        *(u32x2*)(hbase + (size_t)it * (C_ * 2) + 32 * t2) = sv;                 \
      }                                                                          \
    }                                                                            \
  }

  for (int ib = 0; ib < ITS / 2; ++ib) {
    SCAN_STEP(prA, prB, 2 * ib);
    SCAN_STEP(prB, prA, 2 * ib + 1);
  }
#undef SCAN_STEP
}

// ---------------- Kernel 3: projection + LayerNorm + ReLU + residual -------
// (R2 version: 256 threads, LDS overlay ht/yt 36 KB -> 4 WG/CU)
__global__ __launch_bounds__(256) void k_out(const __hip_bfloat16* __restrict__ hcat,
                                             const float* __restrict__ Wp,
                                             const float* __restrict__ bp,
                                             const float* __restrict__ gamma,
                                             const float* __restrict__ beta,
                                             const float* __restrict__ x,
                                             float* __restrict__ out) {
  __shared__ __align__(16) float smem[C_ * 36];   // 9216 floats, overlaid
  __shared__ float2 stats[NT3];
  float (*ht)[36]  = (float(*)[36])smem;          // cc-major, padded
  float (*yt)[260] = (float(*)[260])smem;         // n-major for LN reduce
  const int bid = blockIdx.x;
  const int nb  = bid & 255;           // N/NT3 = 256
  const int b   = bid >> 8;
  const int t   = threadIdx.x;         // = output channel c
  const int lane = t & 63;
  const int wv   = t >> 6;
  const int n0  = nb * NT3;

  const __hip_bfloat16* hsrc = hcat + ((size_t)b * N_ + n0) * C_ + t;
#pragma unroll
  for (int s = 0; s < NT3; ++s)
    ht[t][s] = __bfloat162float(hsrc[(size_t)s * C_]);

  v2f acc2[16];
  const float bpv = bp[t];
#pragma unroll
  for (int j = 0; j < 16; ++j) acc2[j] = mkv2(bpv, bpv);
  __syncthreads();

  const float4* wrow = (const float4*)(Wp + (size_t)t * C_);
#pragma unroll 2
  for (int c4 = 0; c4 < 64; ++c4) {
    float4 w4 = wrow[c4];
    float wq[4] = {w4.x, w4.y, w4.z, w4.w};
#pragma unroll
    for (int q = 0; q < 4; ++q) {
      v2f wqv = mkv2(wq[q], wq[q]);
      const float4* hr = (const float4*)&ht[c4 * 4 + q][0];
#pragma unroll
      for (int j4 = 0; j4 < 8; ++j4) {
        float4 h = hr[j4];
        acc2[j4 * 2 + 0] = __builtin_elementwise_fma(wqv, mkv2(h.x, h.y), acc2[j4 * 2 + 0]);
        acc2[j4 * 2 + 1] = __builtin_elementwise_fma(wqv, mkv2(h.z, h.w), acc2[j4 * 2 + 1]);
      }
    }
  }
  __syncthreads();   // all ht reads done before yt overwrites the buffer
#pragma unroll
  for (int j = 0; j < NT3; ++j) yt[j][t] = acc2[j >> 1][j & 1];
  __syncthreads();
#pragma unroll
  for (int r = 0; r < 8; ++r) {
    const int n = wv * 8 + r;
    float v0 = yt[n][lane], v1 = yt[n][lane + 64];
    float v2 = yt[n][lane + 128], v3 = yt[n][lane + 192];
    float s = v0 + v1 + v2 + v3;
    float qq = v0 * v0 + v1 * v1 + v2 * v2 + v3 * v3;
#pragma unroll
    for (int off = 32; off >= 1; off >>= 1) {
      s  += __shfl_xor(s, off);
      qq += __shfl_xor(qq, off);
    }
    if (lane == 0) {
      float mu  = s * (1.0f / 256.0f);
      float var = qq * (1.0f / 256.0f) - mu * mu;
      var = var < 0.f ? 0.f : var;
      stats[n] = make_float2(mu, rsqrtf(var + 1e-5f));
    }
  }
  __syncthreads();
  const float gm = gamma[t], be = beta[t];
  const float* xr   = x   + ((size_t)b * C_ + t) * N_ + n0;
  float*       orow = out + ((size_t)b * C_ + t) * N_ + n0;
#pragma unroll
  for (int j4 = 0; j4 < 8; ++j4) {
    float4 xv = *(const float4*)(xr + j4 * 4);
    float4 o;
    { float2 st = stats[j4 * 4 + 0];
      float v = (acc2[j4 * 2 + 0].x - st.x) * st.y * gm + be;
      o.x = fmaxf(v, 0.f) + xv.x; }
    { float2 st = stats[j4 * 4 + 1];
      float v = (acc2[j4 * 2 + 0].y - st.x) * st.y * gm + be;
      o.y = fmaxf(v, 0.f) + xv.y; }
    { float2 st = stats[j4 * 4 + 2];
      float v = (acc2[j4 * 2 + 1].x - st.x) * st.y * gm + be;
      o.z = fmaxf(v, 0.f) + xv.z; }
    { float2 st = stats[j4 * 4 + 3];
      float v = (acc2[j4 * 2 + 1].y - st.x) * st.y * gm + be;
      o.w = fmaxf(v, 0.f) + xv.w; }
    *(float4*)(orow + j4 * 4) = o;
  }
}

// ---------------------------------------------------------------------------
extern "C" void kernel_launch(void* const* d_in, const int* in_sizes, int n_in,
                              void* d_out, int out_size, void* d_ws, size_t ws_size,
                              hipStream_t stream) {
  const float* x      = (const float*)d_in[0];
  const float* W_ih   = (const float*)d_in[1];
  const float* W_hh   = (const float*)d_in[2];
  const float* b_ih   = (const float*)d_in[3];
  const float* b_hh   = (const float*)d_in[4];
  const float* W_proj = (const float*)d_in[5];
  const float* b_proj = (const float*)d_in[6];
  const float* gamma  = (const float*)d_in[7];
  const float* beta   = (const float*)d_in[8];
  float* out = (float*)d_out;

  const size_t preElems = (size_t)B_ * G_ * N_ * TH_;   // 50,331,648 bf16
  __hip_bfloat16* pre  = (__hip_bfloat16*)d_ws;
  __hip_bfloat16* hcat = pre + preElems;                // +33.5 MB, total 128 MiB

  k_pre<<<dim3(B_ * G_ * (N_ / NT1)), dim3(192), 0, stream>>>(x, W_ih, b_ih, b_hh, pre);
  k_scan<<<dim3(B_ * G_ * WGRP_), dim3(64), 0, stream>>>(pre, W_hh, b_hh, hcat);
  k_out<<<dim3(B_ * (N_ / NT3)), dim3(256), 0, stream>>>(hcat, W_proj, b_proj,
                                                         gamma, beta, x, out);
}

// Round 8
// 284.110 us; speedup vs baseline: 2.2362x; 1.4660x over previous
//
#include <hip/hip_runtime.h>
#include <hip/hip_bf16.h>

// Problem constants
static constexpr int B_   = 8;
static constexpr int C_   = 256;
static constexpr int N_   = 8192;
static constexpr int G_   = 4;
static constexpr int GS_  = 64;   // group size (= H)
static constexpr int TH_  = 192;  // 3*H
static constexpr int NT3  = 32;   // n-tile for k_out

// MFMA scan: 16 chains per wave, chunked warm-up
static constexpr int CHUNK = 32;         // steps written per chain
static constexpr int WARM  = 64;         // warm-up steps
static constexpr int ITS   = CHUNK + WARM;      // 96 iterations per wave
static constexpr int NCH_  = N_ / CHUNK;        // 256 chunks per (b,g)
static constexpr int WGRP_ = NCH_ / 16;         // 16 waves per (b,g)

typedef float v2f __attribute__((ext_vector_type(2)));
typedef __attribute__((ext_vector_type(8))) short short8;   // 8 bf16 (4 VGPRs)
typedef __attribute__((ext_vector_type(4))) float f32x4;    // MFMA acc
typedef __attribute__((ext_vector_type(2))) unsigned int u32x2;
typedef __attribute__((ext_vector_type(4))) unsigned int u32x4;

__device__ __forceinline__ float fsigmoid(float x) {
  return __builtin_amdgcn_rcpf(1.0f + __expf(-x));
}
__device__ __forceinline__ float ftanh(float x) {
  float e = __expf(2.0f * x);                       // inf-safe: rcp(inf)=0
  return 1.0f - 2.0f * __builtin_amdgcn_rcpf(e + 1.0f);
}
// RNE f32->bf16 pack, 2-in-1 (no builtin on gfx950; asm also blocks remat)
__device__ __forceinline__ unsigned cvtpk(float lo, float hi) {
  unsigned r;
  asm("v_cvt_pk_bf16_f32 %0, %1, %2" : "=v"(r) : "v"(lo), "v"(hi));
  return r;
}
__device__ __forceinline__ f32x4 unpack4(u32x2 p) {
  f32x4 r;
  r[0] = __uint_as_float(p.x << 16);
  r[1] = __uint_as_float(p.x & 0xffff0000u);
  r[2] = __uint_as_float(p.y << 16);
  r[3] = __uint_as_float(p.y & 0xffff0000u);
  return r;
}
__device__ __forceinline__ short8 pack8(const float* f) {
  u32x4 pk;
  pk.x = cvtpk(f[0], f[1]); pk.y = cvtpk(f[2], f[3]);
  pk.z = cvtpk(f[4], f[5]); pk.w = cvtpk(f[6], f[7]);
  return __builtin_bit_cast(short8, pk);
}

// ---------------- Kernel 1: input-gate precompute (MFMA) -------------------
// pre[b][g][n][k] = sum_i x*W_ih + b_ih[k] + (k<128 ? b_hh[k] : 0)   (bf16)
// Per block: (b,g) x 64-n tile. GEMM [192 gates x 64 cc] x [64 cc x 64 n].
__global__ __launch_bounds__(256) void k_pre(const float* __restrict__ x,
                                             const float* __restrict__ W_ih,
                                             const float* __restrict__ b_ih,
                                             const float* __restrict__ b_hh,
                                             __hip_bfloat16* __restrict__ pre) {
  __shared__ __align__(16) unsigned short xb[64][80];   // [n][cc], pad 80
  const int bid = blockIdx.x;
  const int nb  = bid & 127;            // N/64 = 128
  const int bg  = bid >> 7;             // 0..31
  const int g   = bg & 3, b = bg >> 2;
  const int t   = threadIdx.x;
  const int l   = t & 63;
  const int w   = t >> 6;               // wave 0..3
  const int col = l & 15;
  const int q   = l >> 4;
  const int n0  = nb * 64;

  // stage x -> bf16 xb[n][cc]; thread owns cc = t&63, n-quarter t>>6
  {
    const int cc = t & 63;
    const int nq = t >> 6;
    const float* xrow = x + ((size_t)(b * C_ + g * GS_ + cc)) * N_ + n0;
#pragma unroll
    for (int p = 0; p < 4; ++p) {
      const int noff = (nq + p * 4) * 4;         // 0..60
      float4 v = *(const float4*)(xrow + noff);
      unsigned lo = cvtpk(v.x, v.y), hi = cvtpk(v.z, v.w);
      xb[noff + 0][cc] = (unsigned short)(lo & 0xffffu);
      xb[noff + 1][cc] = (unsigned short)(lo >> 16);
      xb[noff + 2][cc] = (unsigned short)(hi & 0xffffu);
      xb[noff + 3][cc] = (unsigned short)(hi >> 16);
    }
  }

  // A-frags: 3 gate-tiles per wave, 2 k-steps; row = col, k = 32kk+8q+e
  short8 a[3][2];
  f32x4 bias[3];
#pragma unroll
  for (int j = 0; j < 3; ++j) {
    const int gt = w * 3 + j;
#pragma unroll
    for (int kk = 0; kk < 2; ++kk) {
      const float* wr = W_ih + ((size_t)g * TH_ + 16 * gt + col) * GS_ + 32 * kk + 8 * q;
      float f8[8];
      float4 w0 = *(const float4*)wr;
      float4 w1 = *(const float4*)(wr + 4);
      f8[0]=w0.x; f8[1]=w0.y; f8[2]=w0.z; f8[3]=w0.w;
      f8[4]=w1.x; f8[5]=w1.y; f8[6]=w1.z; f8[7]=w1.w;
      a[j][kk] = pack8(f8);
    }
    float4 bv = *(const float4*)(b_ih + (size_t)g * TH_ + 16 * gt + 4 * q);
    bias[j][0]=bv.x; bias[j][1]=bv.y; bias[j][2]=bv.z; bias[j][3]=bv.w;
    if (gt < 8) {   // r/z gates: fold b_hh
      float4 hv = *(const float4*)(b_hh + (size_t)g * TH_ + 16 * gt + 4 * q);
      bias[j][0]+=hv.x; bias[j][1]+=hv.y; bias[j][2]+=hv.z; bias[j][3]+=hv.w;
    }
  }
  __syncthreads();

  f32x4 acc[3][4];
#pragma unroll
  for (int j = 0; j < 3; ++j)
#pragma unroll
    for (int nt = 0; nt < 4; ++nt) acc[j][nt] = bias[j];

#pragma unroll
  for (int nt = 0; nt < 4; ++nt) {
    short8 bf0 = *(const short8*)&xb[nt * 16 + col][8 * q];
    short8 bf1 = *(const short8*)&xb[nt * 16 + col][32 + 8 * q];
#pragma unroll
    for (int j = 0; j < 3; ++j) {
      acc[j][nt] = __builtin_amdgcn_mfma_f32_16x16x32_bf16(a[j][0], bf0, acc[j][nt], 0, 0, 0);
      acc[j][nt] = __builtin_amdgcn_mfma_f32_16x16x32_bf16(a[j][1], bf1, acc[j][nt], 0, 0, 0);
    }
  }
  // epilogue: lane holds rows 16gt+4q+0..3 at n = n0+16nt+col -> 8B store
#pragma unroll
  for (int j = 0; j < 3; ++j) {
    const int gt = w * 3 + j;
#pragma unroll
    for (int nt = 0; nt < 4; ++nt) {
      u32x2 sv;
      sv.x = cvtpk(acc[j][nt][0], acc[j][nt][1]);
      sv.y = cvtpk(acc[j][nt][2], acc[j][nt][3]);
      char* dst = (char*)pre + (((size_t)bg * N_ + n0 + nt * 16 + col) * TH_ + 16 * gt + 4 * q) * 2;
      *(u32x2*)dst = sv;
    }
  }
}

// ---------------- Kernel 2: MFMA GRU scan (unchanged from R6) --------------
__global__ __launch_bounds__(64, 1)
void k_scan(const __hip_bfloat16* __restrict__ pre,
            const float* __restrict__ W_hh,
            const float* __restrict__ b_hh,
            __hip_bfloat16* __restrict__ hcat) {
  __shared__ __align__(16) unsigned short HT[16 * 80];  // [chain][80], rows 0..63 used
  const int bid = blockIdx.x;
  const int wg  = bid & (WGRP_ - 1);    // wave-group within bg (0..15)
  const int bg  = bid >> 4;
  const int g   = bg & 3, b = bg >> 2;
  const int l   = threadIdx.x;
  const int c   = l & 15;               // chain column
  const int q   = l >> 4;               // 0..3

  const int cg  = wg * 16 + c;          // global chunk id 0..255
  const int nlo = cg * CHUNK;
  const int n0  = (nlo >= WARM) ? (nlo - WARM) : 0;
  const int wst = nlo - n0;             // write-start iteration (0/32/64)

  short8 a[12][2];
#pragma unroll
  for (int t = 0; t < 12; ++t) {
#pragma unroll
    for (int kk = 0; kk < 2; ++kk) {
      const float* wr = W_hh + ((size_t)g * TH_ + 16 * t + c) * GS_ + 32 * kk + 8 * q;
      float4 w0 = *(const float4*)wr;
      float4 w1 = *(const float4*)(wr + 4);
      u32x4 pk;
      pk.x = cvtpk(w0.x, w0.y); pk.y = cvtpk(w0.z, w0.w);
      pk.z = cvtpk(w1.x, w1.y); pk.w = cvtpk(w1.z, w1.w);
      a[t][kk] = __builtin_bit_cast(short8, pk);
    }
  }
  f32x4 bN[4];
#pragma unroll
  for (int t2 = 0; t2 < 4; ++t2) {
    float4 v = *(const float4*)(b_hh + (size_t)g * TH_ + 128 + 16 * t2 + 4 * q);
    bN[t2][0] = v.x; bN[t2][1] = v.y; bN[t2][2] = v.z; bN[t2][3] = v.w;
  }
  {
    u32x2 z2; z2.x = 0u; z2.y = 0u;
#pragma unroll
    for (int t2 = 0; t2 < 4; ++t2)
      *(u32x2*)((char*)HT + 160 * c + 32 * t2 + 8 * q) = z2;
  }
  const char* pbase = (const char*)pre + ((size_t)bg * N_ + n0) * (TH_ * 2) + 8 * q;
  char* hbase = (char*)hcat + (((size_t)b * N_ + n0) * C_ + g * 64 + 4 * q) * 2;

  u32x2 prA[12], prB[12];
#pragma unroll
  for (int t = 0; t < 12; ++t) prA[t] = *(const u32x2*)(pbase + 32 * t);

  f32x4 h[4];
#pragma unroll
  for (int t2 = 0; t2 < 4; ++t2) { h[t2][0] = 0.f; h[t2][1] = 0.f; h[t2][2] = 0.f; h[t2][3] = 0.f; }

#define SCAN_STEP(CUR, NXT, IT)                                                  \
  {                                                                              \
    const int it = (IT);                                                         \
    _Pragma("unroll")                                                            \
    for (int t = 0; t < 12; ++t)                                                 \
      NXT[t] = *(const u32x2*)(pbase + (size_t)(it + 1) * 384 + 32 * t);         \
    f32x4 acc[12];                                                               \
    f32x4 pN[4];                                                                 \
    _Pragma("unroll")                                                            \
    for (int t2 = 0; t2 < 4; ++t2) {                                             \
      acc[t2]     = unpack4(CUR[t2]);                                            \
      acc[t2 + 4] = unpack4(CUR[t2 + 4]);                                        \
      acc[t2 + 8] = bN[t2];                                                      \
      pN[t2]      = unpack4(CUR[t2 + 8]);                                        \
    }                                                                            \
    short8 bf0 = *(const short8*)((const char*)HT + 160 * c + 16 * q);           \
    short8 bf1 = *(const short8*)((const char*)HT + 160 * c + 16 * q + 64);      \
    _Pragma("unroll")                                                            \
    for (int t = 0; t < 12; ++t) {                                               \
      acc[t] = __builtin_amdgcn_mfma_f32_16x16x32_bf16(a[t][0], bf0, acc[t], 0, 0, 0); \
      acc[t] = __builtin_amdgcn_mfma_f32_16x16x32_bf16(a[t][1], bf1, acc[t], 0, 0, 0); \
    }                                                                            \
    unsigned pk0[4], pk1[4];                                                     \
    _Pragma("unroll")                                                            \
    for (int t2 = 0; t2 < 4; ++t2) {                                             \
      float hn[4];                                                               \
      _Pragma("unroll")                                                          \
      for (int j = 0; j < 4; ++j) {                                              \
        float r  = fsigmoid(acc[t2][j]);                                         \
        float zz = fsigmoid(acc[t2 + 4][j]);                                     \
        float nn = ftanh(fmaf(r, acc[t2 + 8][j], pN[t2][j]));                    \
        float hv = fmaf(zz, h[t2][j] - nn, nn);                                  \
        h[t2][j] = hv; hn[j] = hv;                                               \
      }                                                                          \
      pk0[t2] = cvtpk(hn[0], hn[1]);                                             \
      pk1[t2] = cvtpk(hn[2], hn[3]);                                             \
      u32x2 wv2; wv2.x = pk0[t2]; wv2.y = pk1[t2];                               \
      *(u32x2*)((char*)HT + 160 * c + 32 * t2 + 8 * q) = wv2;                    \
    }                                                                            \
    if (it >= wst && it < wst + CHUNK) {                                         \
      _Pragma("unroll")                                                          \
      for (int t2 = 0; t2 < 4; ++t2) {                                           \
        u32x2 sv; sv.x = pk0[t2]; sv.y = pk1[t2];                                \
        *(u32x2*)(hbase + (size_t)it * (C_ * 2) + 32 * t2) = sv;                 \
      }                                                                          \
    }                                                                            \
  }

  for (int ib = 0; ib < ITS / 2; ++ib) {
    SCAN_STEP(prA, prB, 2 * ib);
    SCAN_STEP(prB, prA, 2 * ib + 1);
  }
#undef SCAN_STEP
}

// ---------------- Kernel 3: MFMA projection + LayerNorm + ReLU + residual --
// Per block: b x 32-n tile. GEMM [256 oc x 256 cc] x [256 cc x 32 n] -> yt,
// then LN reduce + coalesced epilogue (R2 structure).
__global__ __launch_bounds__(256) void k_out(const __hip_bfloat16* __restrict__ hcat,
                                             const float* __restrict__ Wp,
                                             const float* __restrict__ bp,
                                             const float* __restrict__ gamma,
                                             const float* __restrict__ beta,
                                             const float* __restrict__ x,
                                             float* __restrict__ out) {
  __shared__ __align__(16) float yt[NT3][264];   // [n][oc], pad 264 (33.8 KB)
  __shared__ float2 stats[NT3];
  const int bid = blockIdx.x;
  const int nb  = bid & 255;           // N/NT3 = 256
  const int b   = bid >> 8;
  const int t   = threadIdx.x;
  const int l   = t & 63;
  const int w   = t >> 6;              // wave: oc block 64w
  const int col = l & 15;
  const int q   = l >> 4;
  const int n0  = nb * NT3;

  // GEMM: acc[j][nt], oc rows = 64w+16j+4q+reg, n col = n0+16nt+col
  f32x4 acc[4][2];
#pragma unroll
  for (int j = 0; j < 4; ++j) {
    float4 bv = *(const float4*)(bp + 64 * w + 16 * j + 4 * q);
    f32x4 bi; bi[0]=bv.x; bi[1]=bv.y; bi[2]=bv.z; bi[3]=bv.w;
    acc[j][0] = bi; acc[j][1] = bi;
  }
  const unsigned short* hb = (const unsigned short*)hcat;
#pragma unroll
  for (int kk = 0; kk < 8; ++kk) {
    short8 A[4];
#pragma unroll
    for (int j = 0; j < 4; ++j) {
      const float* wr = Wp + ((size_t)(64 * w + 16 * j + col)) * C_ + 32 * kk + 8 * q;
      float f8[8];
      float4 w0 = *(const float4*)wr;
      float4 w1 = *(const float4*)(wr + 4);
      f8[0]=w0.x; f8[1]=w0.y; f8[2]=w0.z; f8[3]=w0.w;
      f8[4]=w1.x; f8[5]=w1.y; f8[6]=w1.z; f8[7]=w1.w;
      A[j] = pack8(f8);
    }
    short8 Bf[2];
#pragma unroll
    for (int nt = 0; nt < 2; ++nt) {
      const unsigned short* hr = hb + ((size_t)b * N_ + n0 + nt * 16 + col) * C_ + 32 * kk + 8 * q;
      Bf[nt] = *(const short8*)hr;
    }
#pragma unroll
    for (int j = 0; j < 4; ++j) {
      acc[j][0] = __builtin_amdgcn_mfma_f32_16x16x32_bf16(A[j], Bf[0], acc[j][0], 0, 0, 0);
      acc[j][1] = __builtin_amdgcn_mfma_f32_16x16x32_bf16(A[j], Bf[1], acc[j][1], 0, 0, 0);
    }
  }
  // stage y tile -> yt[n][oc]
#pragma unroll
  for (int j = 0; j < 4; ++j)
#pragma unroll
    for (int nt = 0; nt < 2; ++nt)
      *(f32x4*)&yt[nt * 16 + col][64 * w + 16 * j + 4 * q] = acc[j][nt];
  __syncthreads();

  // LayerNorm stats: wave-reduce per n
#pragma unroll
  for (int r = 0; r < 8; ++r) {
    const int n = w * 8 + r;
    float v0 = yt[n][l], v1 = yt[n][l + 64];
    float v2 = yt[n][l + 128], v3 = yt[n][l + 192];
    float s  = v0 + v1 + v2 + v3;
    float qq = v0 * v0 + v1 * v1 + v2 * v2 + v3 * v3;
#pragma unroll
    for (int off = 32; off >= 1; off >>= 1) {
      s  += __shfl_xor(s, off);
      qq += __shfl_xor(qq, off);
    }
    if (l == 0) {
      float mu  = s * (1.0f / 256.0f);
      float var = qq * (1.0f / 256.0f) - mu * mu;
      var = var < 0.f ? 0.f : var;
      stats[n] = make_float2(mu, rsqrtf(var + 1e-5f));
    }
  }
  __syncthreads();

  // epilogue: thread t = oc; coalesced x read / out write
  const float gm = gamma[t], be = beta[t];
  const float* xr   = x   + ((size_t)b * C_ + t) * N_ + n0;
  float*       orow = out + ((size_t)b * C_ + t) * N_ + n0;
#pragma unroll
  for (int j4 = 0; j4 < 8; ++j4) {
    float4 xv = *(const float4*)(xr + j4 * 4);
    float4 o;
    { float2 st = stats[j4 * 4 + 0];
      float v = (yt[j4 * 4 + 0][t] - st.x) * st.y * gm + be;
      o.x = fmaxf(v, 0.f) + xv.x; }
    { float2 st = stats[j4 * 4 + 1];
      float v = (yt[j4 * 4 + 1][t] - st.x) * st.y * gm + be;
      o.y = fmaxf(v, 0.f) + xv.y; }
    { float2 st = stats[j4 * 4 + 2];
      float v = (yt[j4 * 4 + 2][t] - st.x) * st.y * gm + be;
      o.z = fmaxf(v, 0.f) + xv.z; }
    { float2 st = stats[j4 * 4 + 3];
      float v = (yt[j4 * 4 + 3][t] - st.x) * st.y * gm + be;
      o.w = fmaxf(v, 0.f) + xv.w; }
    *(float4*)(orow + j4 * 4) = o;
  }
}

// ---------------------------------------------------------------------------
extern "C" void kernel_launch(void* const* d_in, const int* in_sizes, int n_in,
                              void* d_out, int out_size, void* d_ws, size_t ws_size,
                              hipStream_t stream) {
  const float* x      = (const float*)d_in[0];
  const float* W_ih   = (const float*)d_in[1];
  const float* W_hh   = (const float*)d_in[2];
  const float* b_ih   = (const float*)d_in[3];
  const float* b_hh   = (const float*)d_in[4];
  const float* W_proj = (const float*)d_in[5];
  const float* b_proj = (const float*)d_in[6];
  const float* gamma  = (const float*)d_in[7];
  const float* beta   = (const float*)d_in[8];
  float* out = (float*)d_out;

  const size_t preElems = (size_t)B_ * G_ * N_ * TH_;   // 50,331,648 bf16
  __hip_bfloat16* pre  = (__hip_bfloat16*)d_ws;
  __hip_bfloat16* hcat = pre + preElems;                // +33.5 MB, total 128 MiB

  k_pre<<<dim3(B_ * G_ * (N_ / 64)), dim3(256), 0, stream>>>(x, W_ih, b_ih, b_hh, pre);
  k_scan<<<dim3(B_ * G_ * WGRP_), dim3(64), 0, stream>>>(pre, W_hh, b_hh, hcat);
  k_out<<<dim3(B_ * (N_ / NT3)), dim3(256), 0, stream>>>(hcat, W_proj, b_proj,
                                                         gamma, beta, x, out);
}

// Round 9
// 259.836 us; speedup vs baseline: 2.4451x; 1.0934x over previous
//
#include <hip/hip_runtime.h>
#include <hip/hip_bf16.h>

// Problem constants
static constexpr int B_   = 8;
static constexpr int C_   = 256;
static constexpr int N_   = 8192;
static constexpr int G_   = 4;
static constexpr int GS_  = 64;   // group size (= H)
static constexpr int TH_  = 192;  // 3*H
static constexpr int NT3  = 32;   // n-tile for k_out

// MFMA scan: 16 chains per wave, chunked warm-up
static constexpr int CHUNK = 16;         // steps written per chain
static constexpr int WARM  = 48;         // warm-up steps (residual < bf16 noise)
static constexpr int ITS   = CHUNK + WARM;      // 64 iterations per wave
static constexpr int NCH_  = N_ / CHUNK;        // 512 chunks per (b,g)
static constexpr int WGRP_ = NCH_ / 16;         // 32 waves per (b,g) -> 1024 WGs

typedef float v2f __attribute__((ext_vector_type(2)));
typedef __attribute__((ext_vector_type(8))) short short8;   // 8 bf16 (4 VGPRs)
typedef __attribute__((ext_vector_type(4))) float f32x4;    // MFMA acc
typedef __attribute__((ext_vector_type(2))) unsigned int u32x2;
typedef __attribute__((ext_vector_type(4))) unsigned int u32x4;

__device__ __forceinline__ float fsigmoid(float x) {
  return __builtin_amdgcn_rcpf(1.0f + __expf(-x));
}
__device__ __forceinline__ float ftanh(float x) {
  float e = __expf(2.0f * x);                       // inf-safe: rcp(inf)=0
  return 1.0f - 2.0f * __builtin_amdgcn_rcpf(e + 1.0f);
}
// RNE f32->bf16 pack, 2-in-1 (no builtin on gfx950; asm also blocks remat)
__device__ __forceinline__ unsigned cvtpk(float lo, float hi) {
  unsigned r;
  asm("v_cvt_pk_bf16_f32 %0, %1, %2" : "=v"(r) : "v"(lo), "v"(hi));
  return r;
}
__device__ __forceinline__ f32x4 unpack4(u32x2 p) {
  f32x4 r;
  r[0] = __uint_as_float(p.x << 16);
  r[1] = __uint_as_float(p.x & 0xffff0000u);
  r[2] = __uint_as_float(p.y << 16);
  r[3] = __uint_as_float(p.y & 0xffff0000u);
  return r;
}
__device__ __forceinline__ short8 pack8(const float* f) {
  u32x4 pk;
  pk.x = cvtpk(f[0], f[1]); pk.y = cvtpk(f[2], f[3]);
  pk.z = cvtpk(f[4], f[5]); pk.w = cvtpk(f[6], f[7]);
  return __builtin_bit_cast(short8, pk);
}

// ---------------- Kernel 1: input-gate precompute (MFMA) -------------------
// pre[b][g][n][k] = sum_i x*W_ih + b_ih[k] + (k<128 ? b_hh[k] : 0)   (bf16)
// Per block: (b,g) x 64-n tile. GEMM [192 gates x 64 cc] x [64 cc x 64 n].
__global__ __launch_bounds__(256) void k_pre(const float* __restrict__ x,
                                             const float* __restrict__ W_ih,
                                             const float* __restrict__ b_ih,
                                             const float* __restrict__ b_hh,
                                             __hip_bfloat16* __restrict__ pre) {
  __shared__ __align__(16) unsigned short xb[64][80];   // [n][cc], pad 80
  const int bid = blockIdx.x;
  const int nb  = bid & 127;            // N/64 = 128
  const int bg  = bid >> 7;             // 0..31
  const int g   = bg & 3, b = bg >> 2;
  const int t   = threadIdx.x;
  const int l   = t & 63;
  const int w   = t >> 6;               // wave 0..3
  const int col = l & 15;
  const int q   = l >> 4;
  const int n0  = nb * 64;

  // stage x -> bf16 xb[n][cc]; thread owns cc = t&63, n-quarter t>>6
  {
    const int cc = t & 63;
    const int nq = t >> 6;
    const float* xrow = x + ((size_t)(b * C_ + g * GS_ + cc)) * N_ + n0;
#pragma unroll
    for (int p = 0; p < 4; ++p) {
      const int noff = (nq + p * 4) * 4;         // 0..60
      float4 v = *(const float4*)(xrow + noff);
      unsigned lo = cvtpk(v.x, v.y), hi = cvtpk(v.z, v.w);
      xb[noff + 0][cc] = (unsigned short)(lo & 0xffffu);
      xb[noff + 1][cc] = (unsigned short)(lo >> 16);
      xb[noff + 2][cc] = (unsigned short)(hi & 0xffffu);
      xb[noff + 3][cc] = (unsigned short)(hi >> 16);
    }
  }

  // A-frags: 3 gate-tiles per wave, 2 k-steps; row = col, k = 32kk+8q+e
  short8 a[3][2];
  f32x4 bias[3];
#pragma unroll
  for (int j = 0; j < 3; ++j) {
    const int gt = w * 3 + j;
#pragma unroll
    for (int kk = 0; kk < 2; ++kk) {
      const float* wr = W_ih + ((size_t)g * TH_ + 16 * gt + col) * GS_ + 32 * kk + 8 * q;
      float f8[8];
      float4 w0 = *(const float4*)wr;
      float4 w1 = *(const float4*)(wr + 4);
      f8[0]=w0.x; f8[1]=w0.y; f8[2]=w0.z; f8[3]=w0.w;
      f8[4]=w1.x; f8[5]=w1.y; f8[6]=w1.z; f8[7]=w1.w;
      a[j][kk] = pack8(f8);
    }
    float4 bv = *(const float4*)(b_ih + (size_t)g * TH_ + 16 * gt + 4 * q);
    bias[j][0]=bv.x; bias[j][1]=bv.y; bias[j][2]=bv.z; bias[j][3]=bv.w;
    if (gt < 8) {   // r/z gates: fold b_hh
      float4 hv = *(const float4*)(b_hh + (size_t)g * TH_ + 16 * gt + 4 * q);
      bias[j][0]+=hv.x; bias[j][1]+=hv.y; bias[j][2]+=hv.z; bias[j][3]+=hv.w;
    }
  }
  __syncthreads();

  f32x4 acc[3][4];
#pragma unroll
  for (int j = 0; j < 3; ++j)
#pragma unroll
    for (int nt = 0; nt < 4; ++nt) acc[j][nt] = bias[j];

#pragma unroll
  for (int nt = 0; nt < 4; ++nt) {
    short8 bf0 = *(const short8*)&xb[nt * 16 + col][8 * q];
    short8 bf1 = *(const short8*)&xb[nt * 16 + col][32 + 8 * q];
#pragma unroll
    for (int j = 0; j < 3; ++j) {
      acc[j][nt] = __builtin_amdgcn_mfma_f32_16x16x32_bf16(a[j][0], bf0, acc[j][nt], 0, 0, 0);
      acc[j][nt] = __builtin_amdgcn_mfma_f32_16x16x32_bf16(a[j][1], bf1, acc[j][nt], 0, 0, 0);
    }
  }
  // epilogue: lane holds rows 16gt+4q+0..3 at n = n0+16nt+col -> 8B store
#pragma unroll
  for (int j = 0; j < 3; ++j) {
    const int gt = w * 3 + j;
#pragma unroll
    for (int nt = 0; nt < 4; ++nt) {
      u32x2 sv;
      sv.x = cvtpk(acc[j][nt][0], acc[j][nt][1]);
      sv.y = cvtpk(acc[j][nt][2], acc[j][nt][3]);
      char* dst = (char*)pre + (((size_t)bg * N_ + n0 + nt * 16 + col) * TH_ + 16 * gt + 4 * q) * 2;
      *(u32x2*)dst = sv;
    }
  }
}

// ---------------- Kernel 2: MFMA GRU scan ----------------------------------
// 1024 single-wave WGs (1 wave per SIMD chip-wide). 16 chains per wave.
// Distance-2 prefetch: unpack CUR, immediately reload CUR with it+2.
__global__ __launch_bounds__(64, 1)
void k_scan(const __hip_bfloat16* __restrict__ pre,
            const float* __restrict__ W_hh,
            const float* __restrict__ b_hh,
            __hip_bfloat16* __restrict__ hcat) {
  __shared__ __align__(16) unsigned short HT[16 * 80];  // [chain][80], rows 0..63 used
  const int bid = blockIdx.x;
  const int wg  = bid & (WGRP_ - 1);    // wave-group within bg (0..31)
  const int bg  = bid >> 5;
  const int g   = bg & 3, b = bg >> 2;
  const int l   = threadIdx.x;
  const int c   = l & 15;               // chain column
  const int q   = l >> 4;               // 0..3

  const int cg  = wg * 16 + c;          // global chunk id 0..511
  const int nlo = cg * CHUNK;
  const int n0  = (nlo >= WARM) ? (nlo - WARM) : 0;
  const int wst = nlo - n0;             // write-start iteration

  short8 a[12][2];
#pragma unroll
  for (int t = 0; t < 12; ++t) {
#pragma unroll
    for (int kk = 0; kk < 2; ++kk) {
      const float* wr = W_hh + ((size_t)g * TH_ + 16 * t + c) * GS_ + 32 * kk + 8 * q;
      float4 w0 = *(const float4*)wr;
      float4 w1 = *(const float4*)(wr + 4);
      u32x4 pk;
      pk.x = cvtpk(w0.x, w0.y); pk.y = cvtpk(w0.z, w0.w);
      pk.z = cvtpk(w1.x, w1.y); pk.w = cvtpk(w1.z, w1.w);
      a[t][kk] = __builtin_bit_cast(short8, pk);
    }
  }
  f32x4 bN[4];
#pragma unroll
  for (int t2 = 0; t2 < 4; ++t2) {
    float4 v = *(const float4*)(b_hh + (size_t)g * TH_ + 128 + 16 * t2 + 4 * q);
    bN[t2][0] = v.x; bN[t2][1] = v.y; bN[t2][2] = v.z; bN[t2][3] = v.w;
  }
  {
    u32x2 z2; z2.x = 0u; z2.y = 0u;
#pragma unroll
    for (int t2 = 0; t2 < 4; ++t2)
      *(u32x2*)((char*)HT + 160 * c + 32 * t2 + 8 * q) = z2;
  }
  const char* pbase = (const char*)pre + ((size_t)bg * N_ + n0) * (TH_ * 2) + 8 * q;
  char* hbase = (char*)hcat + (((size_t)b * N_ + n0) * C_ + g * 64 + 4 * q) * 2;

  u32x2 prA[12], prB[12];
#pragma unroll
  for (int t = 0; t < 12; ++t) prA[t] = *(const u32x2*)(pbase + 32 * t);
#pragma unroll
  for (int t = 0; t < 12; ++t) prB[t] = *(const u32x2*)(pbase + 384 + 32 * t);

  f32x4 h[4];
#pragma unroll
  for (int t2 = 0; t2 < 4; ++t2) { h[t2][0] = 0.f; h[t2][1] = 0.f; h[t2][2] = 0.f; h[t2][3] = 0.f; }

#define SCAN_STEP(CUR, IT)                                                       \
  {                                                                              \
    const int it = (IT);                                                         \
    f32x4 acc[12];                                                               \
    f32x4 pN[4];                                                                 \
    _Pragma("unroll")                                                            \
    for (int t2 = 0; t2 < 4; ++t2) {                                             \
      acc[t2]     = unpack4(CUR[t2]);                                            \
      acc[t2 + 4] = unpack4(CUR[t2 + 4]);                                        \
      acc[t2 + 8] = bN[t2];                                                      \
      pN[t2]      = unpack4(CUR[t2 + 8]);                                        \
    }                                                                            \
    if (it + 2 < ITS) {                                                          \
      _Pragma("unroll")                                                          \
      for (int t = 0; t < 12; ++t)                                               \
        CUR[t] = *(const u32x2*)(pbase + (size_t)(it + 2) * 384 + 32 * t);       \
    }                                                                            \
    short8 bf0 = *(const short8*)((const char*)HT + 160 * c + 16 * q);           \
    short8 bf1 = *(const short8*)((const char*)HT + 160 * c + 16 * q + 64);      \
    _Pragma("unroll")                                                            \
    for (int t = 0; t < 12; ++t) {                                               \
      acc[t] = __builtin_amdgcn_mfma_f32_16x16x32_bf16(a[t][0], bf0, acc[t], 0, 0, 0); \
      acc[t] = __builtin_amdgcn_mfma_f32_16x16x32_bf16(a[t][1], bf1, acc[t], 0, 0, 0); \
    }                                                                            \
    unsigned pk0[4], pk1[4];                                                     \
    _Pragma("unroll")                                                            \
    for (int t2 = 0; t2 < 4; ++t2) {                                             \
      float hn[4];                                                               \
      _Pragma("unroll")                                                          \
      for (int j = 0; j < 4; ++j) {                                              \
        float r  = fsigmoid(acc[t2][j]);                                         \
        float zz = fsigmoid(acc[t2 + 4][j]);                                     \
        float nn = ftanh(fmaf(r, acc[t2 + 8][j], pN[t2][j]));                    \
        float hv = fmaf(zz, h[t2][j] - nn, nn);                                  \
        h[t2][j] = hv; hn[j] = hv;                                               \
      }                                                                          \
      pk0[t2] = cvtpk(hn[0], hn[1]);                                             \
      pk1[t2] = cvtpk(hn[2], hn[3]);                                             \
      u32x2 wv2; wv2.x = pk0[t2]; wv2.y = pk1[t2];                               \
      *(u32x2*)((char*)HT + 160 * c + 32 * t2 + 8 * q) = wv2;                    \
    }                                                                            \
    if (it >= wst && it < wst + CHUNK) {                                         \
      _Pragma("unroll")                                                          \
      for (int t2 = 0; t2 < 4; ++t2) {                                           \
        u32x2 sv; sv.x = pk0[t2]; sv.y = pk1[t2];                                \
        *(u32x2*)(hbase + (size_t)it * (C_ * 2) + 32 * t2) = sv;                 \
      }                                                                          \
    }                                                                            \
  }

  for (int ib = 0; ib < ITS / 2; ++ib) {
    SCAN_STEP(prA, 2 * ib);
    SCAN_STEP(prB, 2 * ib + 1);
  }
#undef SCAN_STEP
}

// ---------------- Kernel 3: MFMA projection + LayerNorm + ReLU + residual --
// Per block: b x 32-n tile. GEMM [256 oc x 256 cc] x [256 cc x 32 n] -> yt,
// then LN reduce + coalesced epilogue.
__global__ __launch_bounds__(256) void k_out(const __hip_bfloat16* __restrict__ hcat,
                                             const float* __restrict__ Wp,
                                             const float* __restrict__ bp,
                                             const float* __restrict__ gamma,
                                             const float* __restrict__ beta,
                                             const float* __restrict__ x,
                                             float* __restrict__ out) {
  __shared__ __align__(16) float yt[NT3][264];   // [n][oc], pad 264 (33.8 KB)
  __shared__ float2 stats[NT3];
  const int bid = blockIdx.x;
  const int nb  = bid & 255;           // N/NT3 = 256
  const int b   = bid >> 8;
  const int t   = threadIdx.x;
  const int l   = t & 63;
  const int w   = t >> 6;              // wave: oc block 64w
  const int col = l & 15;
  const int q   = l >> 4;
  const int n0  = nb * NT3;

  f32x4 acc[4][2];
#pragma unroll
  for (int j = 0; j < 4; ++j) {
    float4 bv = *(const float4*)(bp + 64 * w + 16 * j + 4 * q);
    f32x4 bi; bi[0]=bv.x; bi[1]=bv.y; bi[2]=bv.z; bi[3]=bv.w;
    acc[j][0] = bi; acc[j][1] = bi;
  }
  const unsigned short* hb = (const unsigned short*)hcat;
#pragma unroll
  for (int kk = 0; kk < 8; ++kk) {
    short8 A[4];
#pragma unroll
    for (int j = 0; j < 4; ++j) {
      const float* wr = Wp + ((size_t)(64 * w + 16 * j + col)) * C_ + 32 * kk + 8 * q;
      float f8[8];
      float4 w0 = *(const float4*)wr;
      float4 w1 = *(const float4*)(wr + 4);
      f8[0]=w0.x; f8[1]=w0.y; f8[2]=w0.z; f8[3]=w0.w;
      f8[4]=w1.x; f8[5]=w1.y; f8[6]=w1.z; f8[7]=w1.w;
      A[j] = pack8(f8);
    }
    short8 Bf[2];
#pragma unroll
    for (int nt = 0; nt < 2; ++nt) {
      const unsigned short* hr = hb + ((size_t)b * N_ + n0 + nt * 16 + col) * C_ + 32 * kk + 8 * q;
      Bf[nt] = *(const short8*)hr;
    }
#pragma unroll
    for (int j = 0; j < 4; ++j) {
      acc[j][0] = __builtin_amdgcn_mfma_f32_16x16x32_bf16(A[j], Bf[0], acc[j][0], 0, 0, 0);
      acc[j][1] = __builtin_amdgcn_mfma_f32_16x16x32_bf16(A[j], Bf[1], acc[j][1], 0, 0, 0);
    }
  }
#pragma unroll
  for (int j = 0; j < 4; ++j)
#pragma unroll
    for (int nt = 0; nt < 2; ++nt)
      *(f32x4*)&yt[nt * 16 + col][64 * w + 16 * j + 4 * q] = acc[j][nt];
  __syncthreads();

#pragma unroll
  for (int r = 0; r < 8; ++r) {
    const int n = w * 8 + r;
    float v0 = yt[n][l], v1 = yt[n][l + 64];
    float v2 = yt[n][l + 128], v3 = yt[n][l + 192];
    float s  = v0 + v1 + v2 + v3;
    float qq = v0 * v0 + v1 * v1 + v2 * v2 + v3 * v3;
#pragma unroll
    for (int off = 32; off >= 1; off >>= 1) {
      s  += __shfl_xor(s, off);
      qq += __shfl_xor(qq, off);
    }
    if (l == 0) {
      float mu  = s * (1.0f / 256.0f);
      float var = qq * (1.0f / 256.0f) - mu * mu;
      var = var < 0.f ? 0.f : var;
      stats[n] = make_float2(mu, rsqrtf(var + 1e-5f));
    }
  }
  __syncthreads();

  const float gm = gamma[t], be = beta[t];
  const float* xr   = x   + ((size_t)b * C_ + t) * N_ + n0;
  float*       orow = out + ((size_t)b * C_ + t) * N_ + n0;
#pragma unroll
  for (int j4 = 0; j4 < 8; ++j4) {
    float4 xv = *(const float4*)(xr + j4 * 4);
    float4 o;
    { float2 st = stats[j4 * 4 + 0];
      float v = (yt[j4 * 4 + 0][t] - st.x) * st.y * gm + be;
      o.x = fmaxf(v, 0.f) + xv.x; }
    { float2 st = stats[j4 * 4 + 1];
      float v = (yt[j4 * 4 + 1][t] - st.x) * st.y * gm + be;
      o.y = fmaxf(v, 0.f) + xv.y; }
    { float2 st = stats[j4 * 4 + 2];
      float v = (yt[j4 * 4 + 2][t] - st.x) * st.y * gm + be;
      o.z = fmaxf(v, 0.f) + xv.z; }
    { float2 st = stats[j4 * 4 + 3];
      float v = (yt[j4 * 4 + 3][t] - st.x) * st.y * gm + be;
      o.w = fmaxf(v, 0.f) + xv.w; }
    *(float4*)(orow + j4 * 4) = o;
  }
}

// ---------------------------------------------------------------------------
extern "C" void kernel_launch(void* const* d_in, const int* in_sizes, int n_in,
                              void* d_out, int out_size, void* d_ws, size_t ws_size,
                              hipStream_t stream) {
  const float* x      = (const float*)d_in[0];
  const float* W_ih   = (const float*)d_in[1];
  const float* W_hh   = (const float*)d_in[2];
  const float* b_ih   = (const float*)d_in[3];
  const float* b_hh   = (const float*)d_in[4];
  const float* W_proj = (const float*)d_in[5];
  const float* b_proj = (const float*)d_in[6];
  const float* gamma  = (const float*)d_in[7];
  const float* beta   = (const float*)d_in[8];
  float* out = (float*)d_out;

  const size_t preElems = (size_t)B_ * G_ * N_ * TH_;   // 50,331,648 bf16
  __hip_bfloat16* pre  = (__hip_bfloat16*)d_ws;
  __hip_bfloat16* hcat = pre + preElems;                // +33.5 MB, total 128 MiB

  k_pre<<<dim3(B_ * G_ * (N_ / 64)), dim3(256), 0, stream>>>(x, W_ih, b_ih, b_hh, pre);
  k_scan<<<dim3(B_ * G_ * WGRP_), dim3(64), 0, stream>>>(pre, W_hh, b_hh, hcat);
  k_out<<<dim3(B_ * (N_ / NT3)), dim3(256), 0, stream>>>(hcat, W_proj, b_proj,
                                                         gamma, beta, x, out);
}